// Round 1
// baseline (5093.114 us; speedup 1.0000x reference)
//
#include <hip/hip_runtime.h>
#include <hip/hip_bf16.h>

// ---------------------------------------------------------------------------
// Conformer block, f32 baseline.
// B=8, T=1024, D=512, HID=1024, C=1024, K=31, H=8, dh=64.  M = B*T = 8192.
// ---------------------------------------------------------------------------

#define M_ROWS 8192

__device__ __forceinline__ float sigmoid_(float v) { return 1.f / (1.f + expf(-v)); }

// ---------------------------------------------------------------------------
// Generic tiled GEMM: C[M,N] = epilogue(A[M,K] @ B + bias), tile 64x64x16.
// TRANSB=false: B is [K,N] row-major.  TRANSB=true: B is [N,K] row-major.
// EPI: 0 = bias; 1 = swish(bias); 2 = res + acc + bias; 3 = res + 0.5*(acc+bias);
//      4 = bias, scatter to (B,H,T,dh) layout (N must be 512).
// ---------------------------------------------------------------------------
template <bool TRANSB, int EPI>
__global__ __launch_bounds__(256) void gemm_kernel(
    const float* __restrict__ A, const float* __restrict__ B,
    const float* __restrict__ bias, const float* __restrict__ res,
    float* __restrict__ C, int M, int N, int K) {
  __shared__ float As[16][68];  // [k][m], +4 pad keeps float4 alignment
  __shared__ float Bs[16][68];  // [k][n]
  const int tid = threadIdx.x;
  const int bm = blockIdx.y << 6, bn = blockIdx.x << 6;
  const int tx = tid & 15, ty = tid >> 4;
  const int lr = tid >> 2;         // 0..63
  const int lk = (tid & 3) << 2;   // 0,4,8,12
  const int bkr = tid >> 4;        // 0..15
  const int bnc = (tid & 15) << 2; // 0..60
  float acc[4][4] = {};
  for (int k0 = 0; k0 < K; k0 += 16) {
    float4 av = *reinterpret_cast<const float4*>(&A[(size_t)(bm + lr) * K + k0 + lk]);
    As[lk + 0][lr] = av.x; As[lk + 1][lr] = av.y;
    As[lk + 2][lr] = av.z; As[lk + 3][lr] = av.w;
    if (!TRANSB) {
      float4 bv = *reinterpret_cast<const float4*>(&B[(size_t)(k0 + bkr) * N + bn + bnc]);
      *reinterpret_cast<float4*>(&Bs[bkr][bnc]) = bv;
    } else {
      float4 bv = *reinterpret_cast<const float4*>(&B[(size_t)(bn + lr) * K + k0 + lk]);
      Bs[lk + 0][lr] = bv.x; Bs[lk + 1][lr] = bv.y;
      Bs[lk + 2][lr] = bv.z; Bs[lk + 3][lr] = bv.w;
    }
    __syncthreads();
#pragma unroll
    for (int kk = 0; kk < 16; ++kk) {
      float4 a4 = *reinterpret_cast<const float4*>(&As[kk][ty << 2]);
      float4 b4 = *reinterpret_cast<const float4*>(&Bs[kk][tx << 2]);
      float a[4] = {a4.x, a4.y, a4.z, a4.w};
      float b[4] = {b4.x, b4.y, b4.z, b4.w};
#pragma unroll
      for (int i = 0; i < 4; ++i)
#pragma unroll
        for (int j = 0; j < 4; ++j) acc[i][j] = fmaf(a[i], b[j], acc[i][j]);
    }
    __syncthreads();
  }
#pragma unroll
  for (int i = 0; i < 4; ++i) {
    const int r = bm + (ty << 2) + i;
#pragma unroll
    for (int j = 0; j < 4; ++j) {
      const int c = bn + (tx << 2) + j;
      float v = acc[i][j] + bias[c];
      if (EPI == 1) v = v * sigmoid_(v);
      if (EPI == 2) v = res[(size_t)r * N + c] + v;
      if (EPI == 3) v = res[(size_t)r * N + c] + 0.5f * v;
      if (EPI == 4) {
        const int b_ = r >> 10, t_ = r & 1023, h_ = c >> 6, d_ = c & 63;
        C[((size_t)((b_ << 3) + h_) * 1024 + t_) * 64 + d_] = v;
      } else {
        C[(size_t)r * N + c] = v;
      }
    }
  }
}

// ---------------------------------------------------------------------------
// LayerNorm over last dim (512). One block (256 threads) per row.
// ---------------------------------------------------------------------------
__global__ __launch_bounds__(256) void ln_kernel(
    const float* __restrict__ in, const float* __restrict__ g,
    const float* __restrict__ b, float* __restrict__ out) {
  __shared__ float sm[4];
  const size_t row = blockIdx.x;
  const int tid = threadIdx.x;
  const float* x = in + (row << 9);
  float v0 = x[tid], v1 = x[tid + 256];
  float s = v0 + v1;
  for (int o = 32; o; o >>= 1) s += __shfl_xor(s, o);
  if ((tid & 63) == 0) sm[tid >> 6] = s;
  __syncthreads();
  const float mean = (sm[0] + sm[1] + sm[2] + sm[3]) * (1.f / 512.f);
  __syncthreads();
  const float d0 = v0 - mean, d1 = v1 - mean;
  float q = d0 * d0 + d1 * d1;
  for (int o = 32; o; o >>= 1) q += __shfl_xor(q, o);
  if ((tid & 63) == 0) sm[tid >> 6] = q;
  __syncthreads();
  const float var = (sm[0] + sm[1] + sm[2] + sm[3]) * (1.f / 512.f);
  const float inv = rsqrtf(var + 1e-5f);
  out[(row << 9) + tid] = d0 * inv * g[tid] + b[tid];
  out[(row << 9) + tid + 256] = d1 * inv * g[tid + 256] + b[tid + 256];
}

// ---------------------------------------------------------------------------
// RoPE in-place on (B,H,T,64). pos_from_t=1: pos = t (for k).
// pos_from_t=0: pos = h (head index! reference applies _rope to q BEFORE the
// transpose, so n = NUM_HEADS).
// ---------------------------------------------------------------------------
__global__ __launch_bounds__(256) void rope_kernel(float* __restrict__ x, int pos_from_t) {
  const size_t i = (size_t)blockIdx.x * 256 + threadIdx.x;  // over B*H*T*32
  const int p = (int)(i & 31);
  const size_t bht = i >> 5;
  const int pos = pos_from_t ? (int)(bht & 1023) : (int)((bht >> 10) & 7);
  const float ang = (float)pos * powf(10000.f, -(float)p * (1.f / 32.f));
  float sn, cs;
  sincosf(ang, &sn, &cs);
  float* base = x + (bht << 6) + (p << 1);
  const float x1 = base[0], x2 = base[1];
  base[0] = x1 * cs - x2 * sn;
  base[1] = x2 * cs + x1 * sn;
}

// ---------------------------------------------------------------------------
// Attention: one block per (b,h,t) query row. Scores in LDS, two-pass softmax.
// q,k,v are (B,H,T,64). ctx written as (B,T,H*64)=(8192,512).
// ---------------------------------------------------------------------------
__global__ __launch_bounds__(256) void attn_kernel(
    const float* __restrict__ q, const float* __restrict__ k,
    const float* __restrict__ v, float* __restrict__ ctx) {
  const int idx = blockIdx.x;  // b*8192 + h*1024 + t
  const int t = idx & 1023;
  const int bh = idx >> 10;
  const int tid = threadIdx.x;
  __shared__ float sc[1024];
  __shared__ float qs[64];
  __shared__ float red[4];
  __shared__ float part[4][64];
  const float* qrow = q + (size_t)idx * 64;
  const float* kb = k + (size_t)bh * 65536;
  const float* vb = v + (size_t)bh * 65536;
  if (tid < 64) qs[tid] = qrow[tid];
  __syncthreads();
  const float scale = 0.04419417382415922f;  // 1/sqrt(512)
  float lmax = -1e30f;
  float myd[4];
#pragma unroll
  for (int ii = 0; ii < 4; ++ii) {
    const int s = tid + (ii << 8);
    const float* kr = kb + (size_t)s * 64;
    float d = 0.f;
#pragma unroll
    for (int i = 0; i < 64; i += 4) {
      float4 kv = *reinterpret_cast<const float4*>(&kr[i]);
      d = fmaf(qs[i], kv.x, fmaf(qs[i + 1], kv.y, fmaf(qs[i + 2], kv.z, fmaf(qs[i + 3], kv.w, d))));
    }
    d *= scale;
    myd[ii] = d;
    lmax = fmaxf(lmax, d);
  }
  for (int o = 32; o; o >>= 1) lmax = fmaxf(lmax, __shfl_xor(lmax, o));
  if ((tid & 63) == 0) red[tid >> 6] = lmax;
  __syncthreads();
  const float m = fmaxf(fmaxf(red[0], red[1]), fmaxf(red[2], red[3]));
  __syncthreads();
  float lsum = 0.f;
#pragma unroll
  for (int ii = 0; ii < 4; ++ii) {
    const float p = expf(myd[ii] - m);
    sc[tid + (ii << 8)] = p;
    lsum += p;
  }
  for (int o = 32; o; o >>= 1) lsum += __shfl_xor(lsum, o);
  if ((tid & 63) == 0) red[tid >> 6] = lsum;
  __syncthreads();  // also makes all sc[] stores visible
  const float inv = 1.f / (red[0] + red[1] + red[2] + red[3]);
  const int w = tid >> 6, lane = tid & 63;
  const float* vw = vb + ((size_t)w << 8) * 64;
  const float* sw = sc + (w << 8);
  float a0 = 0.f;
  for (int s = 0; s < 256; ++s) a0 = fmaf(sw[s], vw[((size_t)s << 6) + lane], a0);
  part[w][lane] = a0;
  __syncthreads();
  if (tid < 64) {
    const int b_ = bh >> 3, h_ = bh & 7;
    const float r = (part[0][tid] + part[1][tid] + part[2][tid] + part[3][tid]) * inv;
    ctx[((size_t)((b_ << 10) | t) << 9) + (h_ << 6) + tid] = r;
  }
}

// ---------------------------------------------------------------------------
// GLU: in (8192,2048) -> out (8192,1024): a * sigmoid(gate)
// ---------------------------------------------------------------------------
__global__ __launch_bounds__(256) void glu_kernel(const float* __restrict__ in,
                                                  float* __restrict__ out) {
  const size_t i = (size_t)blockIdx.x * 256 + threadIdx.x;  // 8192*1024
  const size_t row = i >> 10;
  const int c = (int)(i & 1023);
  const float a = in[(row << 11) + c];
  const float g = in[(row << 11) + 1024 + c];
  out[i] = a * sigmoid_(g);
}

// ---------------------------------------------------------------------------
// Depthwise conv K=31 SAME over time, per channel. in/out (B,T,C)=(8,1024,1024)
// ---------------------------------------------------------------------------
__global__ __launch_bounds__(256) void dwconv_kernel(
    const float* __restrict__ in, const float* __restrict__ w,
    const float* __restrict__ bias, float* __restrict__ out) {
  const size_t i = (size_t)blockIdx.x * 256 + threadIdx.x;  // 8*1024*1024
  const int c = (int)(i & 1023);
  const size_t bt = i >> 10;
  const int t = (int)(bt & 1023);
  const size_t b = bt >> 10;
  float acc = bias[c];
#pragma unroll
  for (int kk = 0; kk < 31; ++kk) {
    const int tt = t + kk - 15;
    if (tt >= 0 && tt < 1024)
      acc = fmaf(in[(b << 20) + ((size_t)tt << 10) + c], w[kk * 1024 + c], acc);
  }
  out[i] = acc;
}

// ---------------------------------------------------------------------------
// BatchNorm over (B,T): two-stage deterministic reduction, then apply+swish.
// ---------------------------------------------------------------------------
__global__ __launch_bounds__(256) void bn_stats_kernel(
    const float* __restrict__ y, float* __restrict__ ps, float* __restrict__ pq) {
  const int tid = threadIdx.x;
  const size_t r0 = (size_t)blockIdx.x * 32;
  float s[4] = {0, 0, 0, 0}, q[4] = {0, 0, 0, 0};
  for (int r = 0; r < 32; ++r) {
    const float* row = y + ((r0 + r) << 10);
#pragma unroll
    for (int j = 0; j < 4; ++j) {
      const float v = row[tid + (j << 8)];
      s[j] += v;
      q[j] = fmaf(v, v, q[j]);
    }
  }
#pragma unroll
  for (int j = 0; j < 4; ++j) {
    ps[(size_t)blockIdx.x * 1024 + tid + (j << 8)] = s[j];
    pq[(size_t)blockIdx.x * 1024 + tid + (j << 8)] = q[j];
  }
}

__global__ __launch_bounds__(256) void bn_finalize_kernel(
    const float* __restrict__ ps, const float* __restrict__ pq, float* __restrict__ stats) {
  const int c = blockIdx.x * 256 + threadIdx.x;  // 0..1023
  float s = 0.f, q = 0.f;
  for (int i = 0; i < 256; ++i) {
    s += ps[i * 1024 + c];
    q += pq[i * 1024 + c];
  }
  const float mean = s * (1.f / 8192.f);
  const float var = q * (1.f / 8192.f) - mean * mean;
  stats[c] = mean;
  stats[1024 + c] = rsqrtf(fmaxf(var, 0.f) + 1e-5f);
}

__global__ __launch_bounds__(256) void bn_apply_kernel(
    float* __restrict__ y, const float* __restrict__ g, const float* __restrict__ b,
    const float* __restrict__ stats) {
  const size_t i = (size_t)blockIdx.x * 256 + threadIdx.x;
  const int c = (int)(i & 1023);
  const float v = (y[i] - stats[c]) * stats[1024 + c] * g[c] + b[c];
  y[i] = v * sigmoid_(v);
}

// ---------------------------------------------------------------------------
extern "C" void kernel_launch(void* const* d_in, const int* in_sizes, int n_in,
                              void* d_out, int out_size, void* d_ws, size_t ws_size,
                              hipStream_t stream) {
  const float* x        = (const float*)d_in[0];
  const float* ffn1_w1  = (const float*)d_in[1];
  const float* ffn1_b1  = (const float*)d_in[2];
  const float* ffn1_w2  = (const float*)d_in[3];
  const float* ffn1_b2  = (const float*)d_in[4];
  const float* ln_att_g = (const float*)d_in[5];
  const float* ln_att_b = (const float*)d_in[6];
  const float* wq       = (const float*)d_in[7];
  const float* bq       = (const float*)d_in[8];
  const float* wk       = (const float*)d_in[9];
  const float* bk       = (const float*)d_in[10];
  const float* wv       = (const float*)d_in[11];
  const float* bv       = (const float*)d_in[12];
  const float* wo       = (const float*)d_in[13];
  const float* bo       = (const float*)d_in[14];
  const float* cln_g    = (const float*)d_in[15];
  const float* cln_b    = (const float*)d_in[16];
  const float* pw1_w    = (const float*)d_in[17];
  const float* pw1_b    = (const float*)d_in[18];
  const float* dw_w     = (const float*)d_in[19];
  const float* dw_b     = (const float*)d_in[20];
  const float* bn_g     = (const float*)d_in[21];
  const float* bn_b     = (const float*)d_in[22];
  const float* pw2_w    = (const float*)d_in[23];
  const float* pw2_b    = (const float*)d_in[24];
  const float* ffn2_w1  = (const float*)d_in[25];
  const float* ffn2_b1  = (const float*)d_in[26];
  const float* ffn2_w2  = (const float*)d_in[27];
  const float* ffn2_b2  = (const float*)d_in[28];
  const float* ln_out_g = (const float*)d_in[29];
  const float* ln_out_b = (const float*)d_in[30];

  float* ws = (float*)d_ws;
  const size_t SZ512 = (size_t)M_ROWS * 512;   // 4,194,304
  const size_t SZ1024 = (size_t)M_ROWS * 1024; // 8,388,608
  float* buf_y = ws;                      // residual stream (8192,512)
  float* buf_t = buf_y + SZ512;           // LN out / ctx (8192,512)
  float* buf_a = buf_t + SZ512;           // big scratch (8192,2048)
  float* buf_b = buf_a + 2 * SZ1024;      // (8192,1024)
  float* ps    = buf_b + SZ1024;          // 256*1024 partial sums
  float* pq    = ps + 256 * 1024;         // 256*1024 partial sumsq
  float* stats = pq + 256 * 1024;         // mean[1024], invstd[1024]
  float* qb = buf_a;                      // (B,H,T,64)
  float* kb = buf_a + SZ512;
  float* vb = buf_a + 2 * SZ512;

  const dim3 blk(256);
  const dim3 g_n512(8, 128), g_n1024(16, 128), g_n2048(32, 128);

  // ---- FFN1: y = x + 0.5*(swish(x@w1+b1)@w2+b2)
  gemm_kernel<false, 1><<<g_n1024, blk, 0, stream>>>(x, ffn1_w1, ffn1_b1, nullptr, buf_a, M_ROWS, 1024, 512);
  gemm_kernel<false, 3><<<g_n512, blk, 0, stream>>>(buf_a, ffn1_w2, ffn1_b2, x, buf_y, M_ROWS, 512, 1024);

  // ---- MHSA
  ln_kernel<<<M_ROWS, blk, 0, stream>>>(buf_y, ln_att_g, ln_att_b, buf_t);
  gemm_kernel<false, 4><<<g_n512, blk, 0, stream>>>(buf_t, wq, bq, nullptr, qb, M_ROWS, 512, 512);
  gemm_kernel<false, 4><<<g_n512, blk, 0, stream>>>(buf_t, wk, bk, nullptr, kb, M_ROWS, 512, 512);
  gemm_kernel<false, 4><<<g_n512, blk, 0, stream>>>(buf_t, wv, bv, nullptr, vb, M_ROWS, 512, 512);
  rope_kernel<<<8192, blk, 0, stream>>>(qb, 0);  // pos = head index (!)
  rope_kernel<<<8192, blk, 0, stream>>>(kb, 1);  // pos = t
  attn_kernel<<<65536, blk, 0, stream>>>(qb, kb, vb, buf_t);
  gemm_kernel<false, 2><<<g_n512, blk, 0, stream>>>(buf_t, wo, bo, buf_y, buf_y, M_ROWS, 512, 512);

  // ---- Conv module
  ln_kernel<<<M_ROWS, blk, 0, stream>>>(buf_y, cln_g, cln_b, buf_t);
  gemm_kernel<true, 0><<<g_n2048, blk, 0, stream>>>(buf_t, pw1_w, pw1_b, nullptr, buf_a, M_ROWS, 2048, 512);
  glu_kernel<<<32768, blk, 0, stream>>>(buf_a, buf_b);
  dwconv_kernel<<<32768, blk, 0, stream>>>(buf_b, dw_w, dw_b, buf_a);
  bn_stats_kernel<<<256, blk, 0, stream>>>(buf_a, ps, pq);
  bn_finalize_kernel<<<4, blk, 0, stream>>>(ps, pq, stats);
  bn_apply_kernel<<<32768, blk, 0, stream>>>(buf_a, bn_g, bn_b, stats);
  gemm_kernel<true, 2><<<g_n512, blk, 0, stream>>>(buf_a, pw2_w, pw2_b, buf_y, buf_y, M_ROWS, 512, 1024);

  // ---- FFN2
  gemm_kernel<false, 1><<<g_n1024, blk, 0, stream>>>(buf_y, ffn2_w1, ffn2_b1, nullptr, buf_a, M_ROWS, 1024, 512);
  gemm_kernel<false, 3><<<g_n512, blk, 0, stream>>>(buf_a, ffn2_w2, ffn2_b2, buf_y, buf_y, M_ROWS, 512, 1024);

  // ---- Final LN -> d_out
  ln_kernel<<<M_ROWS, blk, 0, stream>>>(buf_y, ln_out_g, ln_out_b, (float*)d_out);
}

// Round 2
// 1607.530 us; speedup vs baseline: 3.1683x; 3.1683x over previous
//
#include <hip/hip_runtime.h>
#include <hip/hip_bf16.h>

// ---------------------------------------------------------------------------
// Conformer block, f32 baseline + tiled flash attention.
// B=8, T=1024, D=512, HID=1024, C=1024, K=31, H=8, dh=64.  M = B*T = 8192.
// ---------------------------------------------------------------------------

#define M_ROWS 8192

__device__ __forceinline__ float sigmoid_(float v) { return 1.f / (1.f + expf(-v)); }

// ---------------------------------------------------------------------------
// Generic tiled GEMM: C[M,N] = epilogue(A[M,K] @ B + bias), tile 64x64x16.
// TRANSB=false: B is [K,N] row-major.  TRANSB=true: B is [N,K] row-major.
// EPI: 0 = bias; 1 = swish(bias); 2 = res + acc + bias; 3 = res + 0.5*(acc+bias);
//      4 = bias, scatter to (B,H,T,dh) layout (N must be 512).
// ---------------------------------------------------------------------------
template <bool TRANSB, int EPI>
__global__ __launch_bounds__(256) void gemm_kernel(
    const float* __restrict__ A, const float* __restrict__ B,
    const float* __restrict__ bias, const float* __restrict__ res,
    float* __restrict__ C, int M, int N, int K) {
  __shared__ float As[16][68];  // [k][m]
  __shared__ float Bs[16][68];  // [k][n]
  const int tid = threadIdx.x;
  const int bm = blockIdx.y << 6, bn = blockIdx.x << 6;
  const int tx = tid & 15, ty = tid >> 4;
  const int lr = tid >> 2;         // 0..63
  const int lk = (tid & 3) << 2;   // 0,4,8,12
  const int bkr = tid >> 4;        // 0..15
  const int bnc = (tid & 15) << 2; // 0..60
  float acc[4][4] = {};
  for (int k0 = 0; k0 < K; k0 += 16) {
    float4 av = *reinterpret_cast<const float4*>(&A[(size_t)(bm + lr) * K + k0 + lk]);
    As[lk + 0][lr] = av.x; As[lk + 1][lr] = av.y;
    As[lk + 2][lr] = av.z; As[lk + 3][lr] = av.w;
    if (!TRANSB) {
      float4 bv = *reinterpret_cast<const float4*>(&B[(size_t)(k0 + bkr) * N + bn + bnc]);
      *reinterpret_cast<float4*>(&Bs[bkr][bnc]) = bv;
    } else {
      float4 bv = *reinterpret_cast<const float4*>(&B[(size_t)(bn + lr) * K + k0 + lk]);
      Bs[lk + 0][lr] = bv.x; Bs[lk + 1][lr] = bv.y;
      Bs[lk + 2][lr] = bv.z; Bs[lk + 3][lr] = bv.w;
    }
    __syncthreads();
#pragma unroll
    for (int kk = 0; kk < 16; ++kk) {
      float4 a4 = *reinterpret_cast<const float4*>(&As[kk][ty << 2]);
      float4 b4 = *reinterpret_cast<const float4*>(&Bs[kk][tx << 2]);
      float a[4] = {a4.x, a4.y, a4.z, a4.w};
      float b[4] = {b4.x, b4.y, b4.z, b4.w};
#pragma unroll
      for (int i = 0; i < 4; ++i)
#pragma unroll
        for (int j = 0; j < 4; ++j) acc[i][j] = fmaf(a[i], b[j], acc[i][j]);
    }
    __syncthreads();
  }
#pragma unroll
  for (int i = 0; i < 4; ++i) {
    const int r = bm + (ty << 2) + i;
#pragma unroll
    for (int j = 0; j < 4; ++j) {
      const int c = bn + (tx << 2) + j;
      float v = acc[i][j] + bias[c];
      if (EPI == 1) v = v * sigmoid_(v);
      if (EPI == 2) v = res[(size_t)r * N + c] + v;
      if (EPI == 3) v = res[(size_t)r * N + c] + 0.5f * v;
      if (EPI == 4) {
        const int b_ = r >> 10, t_ = r & 1023, h_ = c >> 6, d_ = c & 63;
        C[((size_t)((b_ << 3) + h_) * 1024 + t_) * 64 + d_] = v;
      } else {
        C[(size_t)r * N + c] = v;
      }
    }
  }
}

// ---------------------------------------------------------------------------
// LayerNorm over last dim (512). One block (256 threads) per row.
// ---------------------------------------------------------------------------
__global__ __launch_bounds__(256) void ln_kernel(
    const float* __restrict__ in, const float* __restrict__ g,
    const float* __restrict__ b, float* __restrict__ out) {
  __shared__ float sm[4];
  const size_t row = blockIdx.x;
  const int tid = threadIdx.x;
  const float* x = in + (row << 9);
  float v0 = x[tid], v1 = x[tid + 256];
  float s = v0 + v1;
  for (int o = 32; o; o >>= 1) s += __shfl_xor(s, o);
  if ((tid & 63) == 0) sm[tid >> 6] = s;
  __syncthreads();
  const float mean = (sm[0] + sm[1] + sm[2] + sm[3]) * (1.f / 512.f);
  __syncthreads();
  const float d0 = v0 - mean, d1 = v1 - mean;
  float q = d0 * d0 + d1 * d1;
  for (int o = 32; o; o >>= 1) q += __shfl_xor(q, o);
  if ((tid & 63) == 0) sm[tid >> 6] = q;
  __syncthreads();
  const float var = (sm[0] + sm[1] + sm[2] + sm[3]) * (1.f / 512.f);
  const float inv = rsqrtf(var + 1e-5f);
  out[(row << 9) + tid] = d0 * inv * g[tid] + b[tid];
  out[(row << 9) + tid + 256] = d1 * inv * g[tid + 256] + b[tid + 256];
}

// ---------------------------------------------------------------------------
// RoPE in-place on (B,H,T,64). pos_from_t=1: pos = t (for k).
// pos_from_t=0: pos = h (head index! reference applies _rope to q BEFORE the
// transpose, so n = NUM_HEADS).
// ---------------------------------------------------------------------------
__global__ __launch_bounds__(256) void rope_kernel(float* __restrict__ x, int pos_from_t) {
  const size_t i = (size_t)blockIdx.x * 256 + threadIdx.x;  // over B*H*T*32
  const int p = (int)(i & 31);
  const size_t bht = i >> 5;
  const int pos = pos_from_t ? (int)(bht & 1023) : (int)((bht >> 10) & 7);
  const float ang = (float)pos * powf(10000.f, -(float)p * (1.f / 32.f));
  float sn, cs;
  sincosf(ang, &sn, &cs);
  float* base = x + (bht << 6) + (p << 1);
  const float x1 = base[0], x2 = base[1];
  base[0] = x1 * cs - x2 * sn;
  base[1] = x2 * cs + x1 * sn;
}

// ---------------------------------------------------------------------------
// Tiled flash attention. One block per (b,h,qtile=64 rows). 256 threads.
// q,k,v are (B,H,T,64). ctx written as (B,T,512).
// Per 64-key tile: K^T,V staged in LDS; S=Q@K^T via 4x4 register tiles;
// online softmax (running m,l per query row); P^T staged; out += P@V.
// ---------------------------------------------------------------------------
__global__ __launch_bounds__(256) void attn_tile_kernel(
    const float* __restrict__ q, const float* __restrict__ k,
    const float* __restrict__ v, float* __restrict__ ctx) {
  __shared__ float qsT[64][68];  // [d][q]
  __shared__ float ksT[64][68];  // [d][k]
  __shared__ float vs[64][68];   // [k][d]
  __shared__ float psT[64][68];  // [k][q]
  const int bx = blockIdx.x;
  const int bh = bx >> 4, qt = bx & 15;
  const int b_ = bh >> 3, h_ = bh & 7;
  const int tid = threadIdx.x;
  const int tx = tid & 15, ty = tid >> 4;
  const int t0 = qt << 6;
  const float scale = 0.04419417382415922f;  // 1/sqrt(512)
  const float* qbase = q + ((size_t)bh << 16);
  const float* kbase = k + ((size_t)bh << 16);
  const float* vbase = v + ((size_t)bh << 16);
  // stage Q transposed (once)
#pragma unroll
  for (int r = 0; r < 4; ++r) {
    const int f = tid + (r << 8);
    const int qr = f >> 4, dc = (f & 15) << 2;
    float4 t = *reinterpret_cast<const float4*>(&qbase[(size_t)(t0 + qr) * 64 + dc]);
    qsT[dc + 0][qr] = t.x; qsT[dc + 1][qr] = t.y;
    qsT[dc + 2][qr] = t.z; qsT[dc + 3][qr] = t.w;
  }
  float m[4] = {-1e30f, -1e30f, -1e30f, -1e30f};
  float l[4] = {0.f, 0.f, 0.f, 0.f};
  float out[4][4] = {};
  for (int k0 = 0; k0 < 1024; k0 += 64) {
    // stage K^T and V for this tile
#pragma unroll
    for (int r = 0; r < 4; ++r) {
      const int f = tid + (r << 8);
      const int kr = f >> 4, dc = (f & 15) << 2;
      float4 t = *reinterpret_cast<const float4*>(&kbase[(size_t)(k0 + kr) * 64 + dc]);
      ksT[dc + 0][kr] = t.x; ksT[dc + 1][kr] = t.y;
      ksT[dc + 2][kr] = t.z; ksT[dc + 3][kr] = t.w;
      float4 tv = *reinterpret_cast<const float4*>(&vbase[(size_t)(k0 + kr) * 64 + dc]);
      *reinterpret_cast<float4*>(&vs[kr][dc]) = tv;
    }
    __syncthreads();
    // S = Q @ K^T  (4x4 micro-tile per thread)
    float acc[4][4] = {};
#pragma unroll 8
    for (int d = 0; d < 64; ++d) {
      float4 a4 = *reinterpret_cast<const float4*>(&qsT[d][ty << 2]);
      float4 b4 = *reinterpret_cast<const float4*>(&ksT[d][tx << 2]);
      float a[4] = {a4.x, a4.y, a4.z, a4.w};
      float b[4] = {b4.x, b4.y, b4.z, b4.w};
#pragma unroll
      for (int i = 0; i < 4; ++i)
#pragma unroll
        for (int j = 0; j < 4; ++j) acc[i][j] = fmaf(a[i], b[j], acc[i][j]);
    }
    // online softmax
    float p[4][4];
#pragma unroll
    for (int i = 0; i < 4; ++i) {
      float s0 = acc[i][0] * scale, s1 = acc[i][1] * scale;
      float s2 = acc[i][2] * scale, s3 = acc[i][3] * scale;
      float rm = fmaxf(fmaxf(s0, s1), fmaxf(s2, s3));
      rm = fmaxf(rm, __shfl_xor(rm, 1));
      rm = fmaxf(rm, __shfl_xor(rm, 2));
      rm = fmaxf(rm, __shfl_xor(rm, 4));
      rm = fmaxf(rm, __shfl_xor(rm, 8));
      const float nm = fmaxf(m[i], rm);
      const float al = __expf(m[i] - nm);
      const float p0 = __expf(s0 - nm), p1 = __expf(s1 - nm);
      const float p2 = __expf(s2 - nm), p3 = __expf(s3 - nm);
      l[i] = l[i] * al + (p0 + p1 + p2 + p3);
      out[i][0] *= al; out[i][1] *= al; out[i][2] *= al; out[i][3] *= al;
      p[i][0] = p0; p[i][1] = p1; p[i][2] = p2; p[i][3] = p3;
      m[i] = nm;
    }
    // write P^T: psT[k=tx*4+j][q=ty*4 .. +3]
#pragma unroll
    for (int j = 0; j < 4; ++j) {
      float4 w = {p[0][j], p[1][j], p[2][j], p[3][j]};
      *reinterpret_cast<float4*>(&psT[(tx << 2) + j][ty << 2]) = w;
    }
    __syncthreads();
    // out += P @ V
#pragma unroll 8
    for (int kk = 0; kk < 64; ++kk) {
      float4 p4 = *reinterpret_cast<const float4*>(&psT[kk][ty << 2]);
      float4 v4 = *reinterpret_cast<const float4*>(&vs[kk][tx << 2]);
      float pa[4] = {p4.x, p4.y, p4.z, p4.w};
      float vb_[4] = {v4.x, v4.y, v4.z, v4.w};
#pragma unroll
      for (int i = 0; i < 4; ++i)
#pragma unroll
        for (int j = 0; j < 4; ++j) out[i][j] = fmaf(pa[i], vb_[j], out[i][j]);
    }
    __syncthreads();
  }
  // final: reduce l across tx lanes, normalize, store
#pragma unroll
  for (int i = 0; i < 4; ++i) {
    float li = l[i];
    li += __shfl_xor(li, 1);
    li += __shfl_xor(li, 2);
    li += __shfl_xor(li, 4);
    li += __shfl_xor(li, 8);
    const float inv = 1.f / li;
    const int t = t0 + (ty << 2) + i;
    float4 w = {out[i][0] * inv, out[i][1] * inv, out[i][2] * inv, out[i][3] * inv};
    *reinterpret_cast<float4*>(&ctx[(((size_t)((b_ << 10) | t)) << 9) + (h_ << 6) + (tx << 2)]) = w;
  }
}

// ---------------------------------------------------------------------------
// GLU: in (8192,2048) -> out (8192,1024): a * sigmoid(gate)
// ---------------------------------------------------------------------------
__global__ __launch_bounds__(256) void glu_kernel(const float* __restrict__ in,
                                                  float* __restrict__ out) {
  const size_t i = (size_t)blockIdx.x * 256 + threadIdx.x;  // 8192*1024
  const size_t row = i >> 10;
  const int c = (int)(i & 1023);
  const float a = in[(row << 11) + c];
  const float g = in[(row << 11) + 1024 + c];
  out[i] = a * sigmoid_(g);
}

// ---------------------------------------------------------------------------
// Depthwise conv K=31 SAME over time, per channel. in/out (B,T,C)=(8,1024,1024)
// ---------------------------------------------------------------------------
__global__ __launch_bounds__(256) void dwconv_kernel(
    const float* __restrict__ in, const float* __restrict__ w,
    const float* __restrict__ bias, float* __restrict__ out) {
  const size_t i = (size_t)blockIdx.x * 256 + threadIdx.x;  // 8*1024*1024
  const int c = (int)(i & 1023);
  const size_t bt = i >> 10;
  const int t = (int)(bt & 1023);
  const size_t b = bt >> 10;
  float acc = bias[c];
#pragma unroll
  for (int kk = 0; kk < 31; ++kk) {
    const int tt = t + kk - 15;
    if (tt >= 0 && tt < 1024)
      acc = fmaf(in[(b << 20) + ((size_t)tt << 10) + c], w[kk * 1024 + c], acc);
  }
  out[i] = acc;
}

// ---------------------------------------------------------------------------
// BatchNorm over (B,T): two-stage deterministic reduction, then apply+swish.
// ---------------------------------------------------------------------------
__global__ __launch_bounds__(256) void bn_stats_kernel(
    const float* __restrict__ y, float* __restrict__ ps, float* __restrict__ pq) {
  const int tid = threadIdx.x;
  const size_t r0 = (size_t)blockIdx.x * 32;
  float s[4] = {0, 0, 0, 0}, q[4] = {0, 0, 0, 0};
  for (int r = 0; r < 32; ++r) {
    const float* row = y + ((r0 + r) << 10);
#pragma unroll
    for (int j = 0; j < 4; ++j) {
      const float v = row[tid + (j << 8)];
      s[j] += v;
      q[j] = fmaf(v, v, q[j]);
    }
  }
#pragma unroll
  for (int j = 0; j < 4; ++j) {
    ps[(size_t)blockIdx.x * 1024 + tid + (j << 8)] = s[j];
    pq[(size_t)blockIdx.x * 1024 + tid + (j << 8)] = q[j];
  }
}

__global__ __launch_bounds__(256) void bn_finalize_kernel(
    const float* __restrict__ ps, const float* __restrict__ pq, float* __restrict__ stats) {
  const int c = blockIdx.x * 256 + threadIdx.x;  // 0..1023
  float s = 0.f, q = 0.f;
  for (int i = 0; i < 256; ++i) {
    s += ps[i * 1024 + c];
    q += pq[i * 1024 + c];
  }
  const float mean = s * (1.f / 8192.f);
  const float var = q * (1.f / 8192.f) - mean * mean;
  stats[c] = mean;
  stats[1024 + c] = rsqrtf(fmaxf(var, 0.f) + 1e-5f);
}

__global__ __launch_bounds__(256) void bn_apply_kernel(
    float* __restrict__ y, const float* __restrict__ g, const float* __restrict__ b,
    const float* __restrict__ stats) {
  const size_t i = (size_t)blockIdx.x * 256 + threadIdx.x;
  const int c = (int)(i & 1023);
  const float v = (y[i] - stats[c]) * stats[1024 + c] * g[c] + b[c];
  y[i] = v * sigmoid_(v);
}

// ---------------------------------------------------------------------------
extern "C" void kernel_launch(void* const* d_in, const int* in_sizes, int n_in,
                              void* d_out, int out_size, void* d_ws, size_t ws_size,
                              hipStream_t stream) {
  const float* x        = (const float*)d_in[0];
  const float* ffn1_w1  = (const float*)d_in[1];
  const float* ffn1_b1  = (const float*)d_in[2];
  const float* ffn1_w2  = (const float*)d_in[3];
  const float* ffn1_b2  = (const float*)d_in[4];
  const float* ln_att_g = (const float*)d_in[5];
  const float* ln_att_b = (const float*)d_in[6];
  const float* wq       = (const float*)d_in[7];
  const float* bq       = (const float*)d_in[8];
  const float* wk       = (const float*)d_in[9];
  const float* bk       = (const float*)d_in[10];
  const float* wv       = (const float*)d_in[11];
  const float* bv       = (const float*)d_in[12];
  const float* wo       = (const float*)d_in[13];
  const float* bo       = (const float*)d_in[14];
  const float* cln_g    = (const float*)d_in[15];
  const float* cln_b    = (const float*)d_in[16];
  const float* pw1_w    = (const float*)d_in[17];
  const float* pw1_b    = (const float*)d_in[18];
  const float* dw_w     = (const float*)d_in[19];
  const float* dw_b     = (const float*)d_in[20];
  const float* bn_g     = (const float*)d_in[21];
  const float* bn_b     = (const float*)d_in[22];
  const float* pw2_w    = (const float*)d_in[23];
  const float* pw2_b    = (const float*)d_in[24];
  const float* ffn2_w1  = (const float*)d_in[25];
  const float* ffn2_b1  = (const float*)d_in[26];
  const float* ffn2_w2  = (const float*)d_in[27];
  const float* ffn2_b2  = (const float*)d_in[28];
  const float* ln_out_g = (const float*)d_in[29];
  const float* ln_out_b = (const float*)d_in[30];

  float* ws = (float*)d_ws;
  const size_t SZ512 = (size_t)M_ROWS * 512;   // 4,194,304
  const size_t SZ1024 = (size_t)M_ROWS * 1024; // 8,388,608
  float* buf_y = ws;                      // residual stream (8192,512)
  float* buf_t = buf_y + SZ512;           // LN out / ctx (8192,512)
  float* buf_a = buf_t + SZ512;           // big scratch (8192,2048)
  float* buf_b = buf_a + 2 * SZ1024;      // (8192,1024)
  float* ps    = buf_b + SZ1024;          // 256*1024 partial sums
  float* pq    = ps + 256 * 1024;         // 256*1024 partial sumsq
  float* stats = pq + 256 * 1024;         // mean[1024], invstd[1024]
  float* qb = buf_a;                      // (B,H,T,64)
  float* kb = buf_a + SZ512;
  float* vb = buf_a + 2 * SZ512;

  const dim3 blk(256);
  const dim3 g_n512(8, 128), g_n1024(16, 128), g_n2048(32, 128);

  // ---- FFN1: y = x + 0.5*(swish(x@w1+b1)@w2+b2)
  gemm_kernel<false, 1><<<g_n1024, blk, 0, stream>>>(x, ffn1_w1, ffn1_b1, nullptr, buf_a, M_ROWS, 1024, 512);
  gemm_kernel<false, 3><<<g_n512, blk, 0, stream>>>(buf_a, ffn1_w2, ffn1_b2, x, buf_y, M_ROWS, 512, 1024);

  // ---- MHSA
  ln_kernel<<<M_ROWS, blk, 0, stream>>>(buf_y, ln_att_g, ln_att_b, buf_t);
  gemm_kernel<false, 4><<<g_n512, blk, 0, stream>>>(buf_t, wq, bq, nullptr, qb, M_ROWS, 512, 512);
  gemm_kernel<false, 4><<<g_n512, blk, 0, stream>>>(buf_t, wk, bk, nullptr, kb, M_ROWS, 512, 512);
  gemm_kernel<false, 4><<<g_n512, blk, 0, stream>>>(buf_t, wv, bv, nullptr, vb, M_ROWS, 512, 512);
  rope_kernel<<<8192, blk, 0, stream>>>(qb, 0);  // pos = head index (!)
  rope_kernel<<<8192, blk, 0, stream>>>(kb, 1);  // pos = t
  attn_tile_kernel<<<1024, blk, 0, stream>>>(qb, kb, vb, buf_t);
  gemm_kernel<false, 2><<<g_n512, blk, 0, stream>>>(buf_t, wo, bo, buf_y, buf_y, M_ROWS, 512, 512);

  // ---- Conv module
  ln_kernel<<<M_ROWS, blk, 0, stream>>>(buf_y, cln_g, cln_b, buf_t);
  gemm_kernel<true, 0><<<g_n2048, blk, 0, stream>>>(buf_t, pw1_w, pw1_b, nullptr, buf_a, M_ROWS, 2048, 512);
  glu_kernel<<<32768, blk, 0, stream>>>(buf_a, buf_b);
  dwconv_kernel<<<32768, blk, 0, stream>>>(buf_b, dw_w, dw_b, buf_a);
  bn_stats_kernel<<<256, blk, 0, stream>>>(buf_a, ps, pq);
  bn_finalize_kernel<<<4, blk, 0, stream>>>(ps, pq, stats);
  bn_apply_kernel<<<32768, blk, 0, stream>>>(buf_a, bn_g, bn_b, stats);
  gemm_kernel<true, 2><<<g_n512, blk, 0, stream>>>(buf_a, pw2_w, pw2_b, buf_y, buf_y, M_ROWS, 512, 1024);

  // ---- FFN2
  gemm_kernel<false, 1><<<g_n1024, blk, 0, stream>>>(buf_y, ffn2_w1, ffn2_b1, nullptr, buf_a, M_ROWS, 1024, 512);
  gemm_kernel<false, 3><<<g_n512, blk, 0, stream>>>(buf_a, ffn2_w2, ffn2_b2, buf_y, buf_y, M_ROWS, 512, 1024);

  // ---- Final LN -> d_out
  ln_kernel<<<M_ROWS, blk, 0, stream>>>(buf_y, ln_out_g, ln_out_b, (float*)d_out);
}

// Round 3
// 650.579 us; speedup vs baseline: 7.8286x; 2.4709x over previous
//
#include <hip/hip_runtime.h>
#include <hip/hip_bf16.h>

// ---------------------------------------------------------------------------
// Conformer block: bf16-MFMA GEMMs + f32 flash attention.
// B=8, T=1024, D=512, HID=1024, C=1024, K=31, H=8, dh=64.  M = B*T = 8192.
// ---------------------------------------------------------------------------

#define M_ROWS 8192

using bf16x8 = __attribute__((ext_vector_type(8))) short;
using f32x4  = __attribute__((ext_vector_type(4))) float;
using s8v    = __attribute__((ext_vector_type(8))) short;
using s4v    = __attribute__((ext_vector_type(4))) short;

__device__ __forceinline__ float sigmoid_(float v) { return 1.f / (1.f + expf(-v)); }

__device__ __forceinline__ float bf2f(short s) {
  return __uint_as_float(((unsigned)(unsigned short)s) << 16);
}
__device__ __forceinline__ short f2bf(float f) {
  unsigned u = __float_as_uint(f);
  unsigned r = (u + 0x7fffu + ((u >> 16) & 1u)) >> 16;
  return (short)r;
}

__device__ __forceinline__ void gl16(const void* g, void* l) {
  __builtin_amdgcn_global_load_lds((const __attribute__((address_space(1))) void*)g,
                                   (__attribute__((address_space(3))) void*)l, 16, 0, 0);
}

// ---------------------------------------------------------------------------
// bf16 MFMA GEMM: C[M,N] = epi(A[M,K] @ Bt[N,K]^T + bias). BM=128, BK=32.
// 256 threads = 4 waves, wave (wr,wc) owns 64 x BN/2; 16x16x32 MFMA frags.
// EPI: 0 bias->f32 | 1 swish->bf16 | 2 res+acc+bias->f32 (+DUAL bf16)
//      3 res+0.5*(acc+bias)->f32 | 4 bias->f32 scatter to q/k/v (B,H,T,64)
//      5 bias->bf16
// ---------------------------------------------------------------------------
template <int BN, int EPI, bool DUAL>
__global__ __launch_bounds__(256) void mgemm(
    const short* __restrict__ A, const short* __restrict__ Bt,
    const float* __restrict__ bias, const float* __restrict__ res,
    float* __restrict__ out, short* __restrict__ outb, int M, int N, int K) {
  constexpr int NF = BN / 32;
  __shared__ __align__(16) short As[128 * 32];
  __shared__ __align__(16) short Bs[BN * 32];
  const int tid = threadIdx.x;
  const int lane = tid & 63, wid = tid >> 6;
  const int wr = wid >> 1, wc = wid & 1;
  const int bm = blockIdx.y << 7, bn = blockIdx.x * BN;
  f32x4 acc[4][NF];
#pragma unroll
  for (int m = 0; m < 4; ++m)
#pragma unroll
    for (int n = 0; n < NF; ++n) acc[m][n] = (f32x4){0.f, 0.f, 0.f, 0.f};
  const short* Ablk = A + (size_t)bm * K;
  const short* Bblk = Bt + (size_t)bn * K;
  const int r0 = tid >> 2, ks = (tid & 3) << 3;  // staging row / k-offset
  for (int k0 = 0; k0 < K; k0 += 32) {
    gl16(Ablk + (size_t)r0 * K + k0 + ks, (char*)As + wid * 1024);
    gl16(Ablk + (size_t)(r0 + 64) * K + k0 + ks, (char*)As + 4096 + wid * 1024);
    gl16(Bblk + (size_t)r0 * K + k0 + ks, (char*)Bs + wid * 1024);
    if (BN == 128)
      gl16(Bblk + (size_t)(r0 + 64) * K + k0 + ks, (char*)Bs + 4096 + wid * 1024);
    __syncthreads();
    bf16x8 af[4], bfr[NF];
    const int arow = wr * 64 + (lane & 15);
    const int brow = wc * (BN / 2) + (lane & 15);
    const int koff = (lane >> 4) << 3;
#pragma unroll
    for (int m = 0; m < 4; ++m)
      af[m] = *reinterpret_cast<const bf16x8*>(&As[(arow + m * 16) * 32 + koff]);
#pragma unroll
    for (int n = 0; n < NF; ++n)
      bfr[n] = *reinterpret_cast<const bf16x8*>(&Bs[(brow + n * 16) * 32 + koff]);
#pragma unroll
    for (int m = 0; m < 4; ++m)
#pragma unroll
      for (int n = 0; n < NF; ++n)
        acc[m][n] = __builtin_amdgcn_mfma_f32_16x16x32_bf16(af[m], bfr[n], acc[m][n], 0, 0, 0);
    __syncthreads();
  }
  const int orow0 = bm + wr * 64 + ((lane >> 4) << 2);
  const int ocol0 = bn + wc * (BN / 2) + (lane & 15);
#pragma unroll
  for (int m = 0; m < 4; ++m) {
#pragma unroll
    for (int n = 0; n < NF; ++n) {
      const int col = ocol0 + n * 16;
      const float bv = bias[col];
#pragma unroll
      for (int r = 0; r < 4; ++r) {
        const int row = orow0 + m * 16 + r;
        float v = acc[m][n][r] + bv;
        if constexpr (EPI == 0) {
          out[(size_t)row * N + col] = v;
        } else if constexpr (EPI == 1) {
          v = v * sigmoid_(v);
          outb[(size_t)row * N + col] = f2bf(v);
        } else if constexpr (EPI == 2) {
          v += res[(size_t)row * N + col];
          out[(size_t)row * N + col] = v;
          if constexpr (DUAL) outb[(size_t)row * N + col] = f2bf(v);
        } else if constexpr (EPI == 3) {
          v = res[(size_t)row * N + col] + 0.5f * v;
          out[(size_t)row * N + col] = v;
        } else if constexpr (EPI == 4) {
          const int sel = col >> 9, cc = col & 511, h = cc >> 6, d = cc & 63;
          const int b_ = row >> 10, t_ = row & 1023;
          out[(size_t)sel * 4194304 + (((size_t)((b_ << 3) + h) << 10) + t_) * 64 + d] = v;
        } else if constexpr (EPI == 5) {
          outb[(size_t)row * N + col] = f2bf(v);
        }
      }
    }
  }
}

// ---------------------------------------------------------------------------
// LayerNorm over last dim (512). One block (256 threads) per row. OT: float/short(bf16)
// ---------------------------------------------------------------------------
template <typename OT>
__global__ __launch_bounds__(256) void ln_kernel(
    const float* __restrict__ in, const float* __restrict__ g,
    const float* __restrict__ b, OT* __restrict__ out) {
  __shared__ float sm[4];
  const size_t row = blockIdx.x;
  const int tid = threadIdx.x;
  const float* x = in + (row << 9);
  float v0 = x[tid], v1 = x[tid + 256];
  float s = v0 + v1;
  for (int o = 32; o; o >>= 1) s += __shfl_xor(s, o);
  if ((tid & 63) == 0) sm[tid >> 6] = s;
  __syncthreads();
  const float mean = (sm[0] + sm[1] + sm[2] + sm[3]) * (1.f / 512.f);
  __syncthreads();
  const float d0 = v0 - mean, d1 = v1 - mean;
  float q = d0 * d0 + d1 * d1;
  for (int o = 32; o; o >>= 1) q += __shfl_xor(q, o);
  if ((tid & 63) == 0) sm[tid >> 6] = q;
  __syncthreads();
  const float var = (sm[0] + sm[1] + sm[2] + sm[3]) * (1.f / 512.f);
  const float inv = rsqrtf(var + 1e-5f);
  const float o0 = d0 * inv * g[tid] + b[tid];
  const float o1 = d1 * inv * g[tid + 256] + b[tid + 256];
  if constexpr (sizeof(OT) == 2) {
    out[(row << 9) + tid] = f2bf(o0);
    out[(row << 9) + tid + 256] = f2bf(o1);
  } else {
    out[(row << 9) + tid] = o0;
    out[(row << 9) + tid + 256] = o1;
  }
}

// ---------------------------------------------------------------------------
// RoPE in-place on (B,H,T,64) f32. pos_from_t=1: pos=t (k). 0: pos=h (q!).
// ---------------------------------------------------------------------------
__global__ __launch_bounds__(256) void rope_kernel(float* __restrict__ x, int pos_from_t) {
  const size_t i = (size_t)blockIdx.x * 256 + threadIdx.x;  // over B*H*T*32
  const int p = (int)(i & 31);
  const size_t bht = i >> 5;
  const int pos = pos_from_t ? (int)(bht & 1023) : (int)((bht >> 10) & 7);
  const float ang = (float)pos * powf(10000.f, -(float)p * (1.f / 32.f));
  float sn, cs;
  sincosf(ang, &sn, &cs);
  float* base = x + (bht << 6) + (p << 1);
  const float x1 = base[0], x2 = base[1];
  base[0] = x1 * cs - x2 * sn;
  base[1] = x2 * cs + x1 * sn;
}

// ---------------------------------------------------------------------------
// Tiled flash attention (f32 in, bf16 ctx out). One block per (b,h,64-q-tile).
// ---------------------------------------------------------------------------
__global__ __launch_bounds__(256) void attn_tile_kernel(
    const float* __restrict__ q, const float* __restrict__ k,
    const float* __restrict__ v, short* __restrict__ ctx) {
  __shared__ float qsT[64][68];
  __shared__ float ksT[64][68];
  __shared__ float vs[64][68];
  __shared__ float psT[64][68];
  const int bx = blockIdx.x;
  const int bh = bx >> 4, qt = bx & 15;
  const int b_ = bh >> 3, h_ = bh & 7;
  const int tid = threadIdx.x;
  const int tx = tid & 15, ty = tid >> 4;
  const int t0 = qt << 6;
  const float scale = 0.04419417382415922f;  // 1/sqrt(512)
  const float* qbase = q + ((size_t)bh << 16);
  const float* kbase = k + ((size_t)bh << 16);
  const float* vbase = v + ((size_t)bh << 16);
#pragma unroll
  for (int r = 0; r < 4; ++r) {
    const int f = tid + (r << 8);
    const int qr = f >> 4, dc = (f & 15) << 2;
    float4 t = *reinterpret_cast<const float4*>(&qbase[(size_t)(t0 + qr) * 64 + dc]);
    qsT[dc + 0][qr] = t.x; qsT[dc + 1][qr] = t.y;
    qsT[dc + 2][qr] = t.z; qsT[dc + 3][qr] = t.w;
  }
  float m[4] = {-1e30f, -1e30f, -1e30f, -1e30f};
  float l[4] = {0.f, 0.f, 0.f, 0.f};
  float out[4][4] = {};
  for (int k0 = 0; k0 < 1024; k0 += 64) {
#pragma unroll
    for (int r = 0; r < 4; ++r) {
      const int f = tid + (r << 8);
      const int kr = f >> 4, dc = (f & 15) << 2;
      float4 t = *reinterpret_cast<const float4*>(&kbase[(size_t)(k0 + kr) * 64 + dc]);
      ksT[dc + 0][kr] = t.x; ksT[dc + 1][kr] = t.y;
      ksT[dc + 2][kr] = t.z; ksT[dc + 3][kr] = t.w;
      float4 tv = *reinterpret_cast<const float4*>(&vbase[(size_t)(k0 + kr) * 64 + dc]);
      *reinterpret_cast<float4*>(&vs[kr][dc]) = tv;
    }
    __syncthreads();
    float acc[4][4] = {};
#pragma unroll 8
    for (int d = 0; d < 64; ++d) {
      float4 a4 = *reinterpret_cast<const float4*>(&qsT[d][ty << 2]);
      float4 b4 = *reinterpret_cast<const float4*>(&ksT[d][tx << 2]);
      float a[4] = {a4.x, a4.y, a4.z, a4.w};
      float b[4] = {b4.x, b4.y, b4.z, b4.w};
#pragma unroll
      for (int i = 0; i < 4; ++i)
#pragma unroll
        for (int j = 0; j < 4; ++j) acc[i][j] = fmaf(a[i], b[j], acc[i][j]);
    }
    float p[4][4];
#pragma unroll
    for (int i = 0; i < 4; ++i) {
      float s0 = acc[i][0] * scale, s1 = acc[i][1] * scale;
      float s2 = acc[i][2] * scale, s3 = acc[i][3] * scale;
      float rm = fmaxf(fmaxf(s0, s1), fmaxf(s2, s3));
      rm = fmaxf(rm, __shfl_xor(rm, 1));
      rm = fmaxf(rm, __shfl_xor(rm, 2));
      rm = fmaxf(rm, __shfl_xor(rm, 4));
      rm = fmaxf(rm, __shfl_xor(rm, 8));
      const float nm = fmaxf(m[i], rm);
      const float al = __expf(m[i] - nm);
      const float p0 = __expf(s0 - nm), p1 = __expf(s1 - nm);
      const float p2 = __expf(s2 - nm), p3 = __expf(s3 - nm);
      l[i] = l[i] * al + (p0 + p1 + p2 + p3);
      out[i][0] *= al; out[i][1] *= al; out[i][2] *= al; out[i][3] *= al;
      p[i][0] = p0; p[i][1] = p1; p[i][2] = p2; p[i][3] = p3;
      m[i] = nm;
    }
#pragma unroll
    for (int j = 0; j < 4; ++j) {
      float4 w = {p[0][j], p[1][j], p[2][j], p[3][j]};
      *reinterpret_cast<float4*>(&psT[(tx << 2) + j][ty << 2]) = w;
    }
    __syncthreads();
#pragma unroll 8
    for (int kk = 0; kk < 64; ++kk) {
      float4 p4 = *reinterpret_cast<const float4*>(&psT[kk][ty << 2]);
      float4 v4 = *reinterpret_cast<const float4*>(&vs[kk][tx << 2]);
      float pa[4] = {p4.x, p4.y, p4.z, p4.w};
      float vb_[4] = {v4.x, v4.y, v4.z, v4.w};
#pragma unroll
      for (int i = 0; i < 4; ++i)
#pragma unroll
        for (int j = 0; j < 4; ++j) out[i][j] = fmaf(pa[i], vb_[j], out[i][j]);
    }
    __syncthreads();
  }
#pragma unroll
  for (int i = 0; i < 4; ++i) {
    float li = l[i];
    li += __shfl_xor(li, 1);
    li += __shfl_xor(li, 2);
    li += __shfl_xor(li, 4);
    li += __shfl_xor(li, 8);
    const float inv = 1.f / li;
    const int t = t0 + (ty << 2) + i;
    s4v pk = { f2bf(out[i][0] * inv), f2bf(out[i][1] * inv),
               f2bf(out[i][2] * inv), f2bf(out[i][3] * inv) };
    *reinterpret_cast<s4v*>(&ctx[(((size_t)((b_ << 10) | t)) << 9) + (h_ << 6) + (tx << 2)]) = pk;
  }
}

// ---------------------------------------------------------------------------
// f32 -> bf16 cast (8 elems/thread).
// ---------------------------------------------------------------------------
__global__ __launch_bounds__(256) void cast_bf16_kernel(const float* __restrict__ in,
                                                        short* __restrict__ out) {
  const size_t i = (size_t)blockIdx.x * 256 + threadIdx.x;
  const float4 a = *reinterpret_cast<const float4*>(&in[i * 8]);
  const float4 b = *reinterpret_cast<const float4*>(&in[i * 8 + 4]);
  s8v o = { f2bf(a.x), f2bf(a.y), f2bf(a.z), f2bf(a.w),
            f2bf(b.x), f2bf(b.y), f2bf(b.z), f2bf(b.w) };
  *reinterpret_cast<s8v*>(&out[i * 8]) = o;
}

// ---------------------------------------------------------------------------
// Transpose-cast: in [K,N] f32 -> out [N,K] bf16. Grid (N/32, K/32).
// ---------------------------------------------------------------------------
__global__ __launch_bounds__(256) void tcast_kernel(const float* __restrict__ in,
                                                    short* __restrict__ out, int K, int N) {
  __shared__ float t[32][33];
  const int n0 = blockIdx.x << 5, k0 = blockIdx.y << 5;
  const int tx = threadIdx.x & 31, ty = threadIdx.x >> 5;
  for (int r = ty; r < 32; r += 8) t[r][tx] = in[(size_t)(k0 + r) * N + n0 + tx];
  __syncthreads();
  for (int r = ty; r < 32; r += 8) out[(size_t)(n0 + r) * K + k0 + tx] = f2bf(t[tx][r]);
}

__global__ __launch_bounds__(256) void concat3_kernel(const float* a, const float* b,
                                                      const float* c, float* o) {
  const int i = blockIdx.x * 256 + threadIdx.x;  // 1536
  o[i] = i < 512 ? a[i] : (i < 1024 ? b[i - 512] : c[i - 1024]);
}

// ---------------------------------------------------------------------------
// GLU: in bf16 (8192,2048) -> out bf16 (8192,1024). 8 ch/thread.
// ---------------------------------------------------------------------------
__global__ __launch_bounds__(256) void glu_kernel(const short* __restrict__ in,
                                                  short* __restrict__ out) {
  const size_t i = (size_t)blockIdx.x * 256 + threadIdx.x;  // 1M
  const size_t row = i >> 7;
  const int c8 = (int)(i & 127) << 3;
  const s8v av = *reinterpret_cast<const s8v*>(&in[(row << 11) + c8]);
  const s8v gv = *reinterpret_cast<const s8v*>(&in[(row << 11) + 1024 + c8]);
  s8v o;
#pragma unroll
  for (int j = 0; j < 8; ++j) {
    const float a = bf2f(av[j]), g = bf2f(gv[j]);
    o[j] = f2bf(a * sigmoid_(g));
  }
  *reinterpret_cast<s8v*>(&out[i << 3]) = o;
}

// ---------------------------------------------------------------------------
// Depthwise conv K=31 SAME. in bf16 (8,1024,1024), out f32. 8 ch/thread.
// ---------------------------------------------------------------------------
__global__ __launch_bounds__(256) void dwconv_kernel(
    const short* __restrict__ in, const float* __restrict__ w,
    const float* __restrict__ bias, float* __restrict__ out) {
  const size_t i = (size_t)blockIdx.x * 256 + threadIdx.x;  // 1M
  const int c8 = (int)(i & 127) << 3;
  const size_t bt = i >> 7;
  const int t = (int)(bt & 1023);
  const size_t b = bt >> 10;
  float acc[8];
#pragma unroll
  for (int j = 0; j < 8; ++j) acc[j] = bias[c8 + j];
#pragma unroll
  for (int kk = 0; kk < 31; ++kk) {
    const int tt = t + kk - 15;
    if (tt >= 0 && tt < 1024) {
      const s8v xv = *reinterpret_cast<const s8v*>(&in[(b << 20) + ((size_t)tt << 10) + c8]);
      const float4 w0 = *reinterpret_cast<const float4*>(&w[kk * 1024 + c8]);
      const float4 w1 = *reinterpret_cast<const float4*>(&w[kk * 1024 + c8 + 4]);
      acc[0] = fmaf(bf2f(xv[0]), w0.x, acc[0]);
      acc[1] = fmaf(bf2f(xv[1]), w0.y, acc[1]);
      acc[2] = fmaf(bf2f(xv[2]), w0.z, acc[2]);
      acc[3] = fmaf(bf2f(xv[3]), w0.w, acc[3]);
      acc[4] = fmaf(bf2f(xv[4]), w1.x, acc[4]);
      acc[5] = fmaf(bf2f(xv[5]), w1.y, acc[5]);
      acc[6] = fmaf(bf2f(xv[6]), w1.z, acc[6]);
      acc[7] = fmaf(bf2f(xv[7]), w1.w, acc[7]);
    }
  }
  float4 o0 = {acc[0], acc[1], acc[2], acc[3]};
  float4 o1 = {acc[4], acc[5], acc[6], acc[7]};
  *reinterpret_cast<float4*>(&out[(i << 3)]) = o0;
  *reinterpret_cast<float4*>(&out[(i << 3) + 4]) = o1;
}

// ---------------------------------------------------------------------------
// BatchNorm over (B,T): two-stage deterministic reduction; apply+swish -> bf16.
// ---------------------------------------------------------------------------
__global__ __launch_bounds__(256) void bn_stats_kernel(
    const float* __restrict__ y, float* __restrict__ ps, float* __restrict__ pq) {
  const int tid = threadIdx.x;
  const size_t r0 = (size_t)blockIdx.x * 32;
  float s[4] = {0, 0, 0, 0}, q[4] = {0, 0, 0, 0};
  for (int r = 0; r < 32; ++r) {
    const float* row = y + ((r0 + r) << 10);
#pragma unroll
    for (int j = 0; j < 4; ++j) {
      const float v = row[tid + (j << 8)];
      s[j] += v;
      q[j] = fmaf(v, v, q[j]);
    }
  }
#pragma unroll
  for (int j = 0; j < 4; ++j) {
    ps[(size_t)blockIdx.x * 1024 + tid + (j << 8)] = s[j];
    pq[(size_t)blockIdx.x * 1024 + tid + (j << 8)] = q[j];
  }
}

__global__ __launch_bounds__(256) void bn_finalize_kernel(
    const float* __restrict__ ps, const float* __restrict__ pq, float* __restrict__ stats) {
  const int c = blockIdx.x * 256 + threadIdx.x;  // 0..1023
  float s = 0.f, q = 0.f;
  for (int i = 0; i < 256; ++i) {
    s += ps[i * 1024 + c];
    q += pq[i * 1024 + c];
  }
  const float mean = s * (1.f / 8192.f);
  const float var = q * (1.f / 8192.f) - mean * mean;
  stats[c] = mean;
  stats[1024 + c] = rsqrtf(fmaxf(var, 0.f) + 1e-5f);
}

__global__ __launch_bounds__(256) void bn_apply_kernel(
    const float* __restrict__ y, const float* __restrict__ g, const float* __restrict__ b,
    const float* __restrict__ stats, short* __restrict__ out) {
  const size_t i = (size_t)blockIdx.x * 256 + threadIdx.x;  // 2M, 4 elems each
  const size_t f = i << 2;
  const int c = (int)(f & 1023);
  const float4 yv = *reinterpret_cast<const float4*>(&y[f]);
  s4v o;
  float vv[4] = {yv.x, yv.y, yv.z, yv.w};
#pragma unroll
  for (int j = 0; j < 4; ++j) {
    const float v = (vv[j] - stats[c + j]) * stats[1024 + c + j] * g[c + j] + b[c + j];
    o[j] = f2bf(v * sigmoid_(v));
  }
  *reinterpret_cast<s4v*>(&out[f]) = o;
}

// ---------------------------------------------------------------------------
extern "C" void kernel_launch(void* const* d_in, const int* in_sizes, int n_in,
                              void* d_out, int out_size, void* d_ws, size_t ws_size,
                              hipStream_t stream) {
  const float* x        = (const float*)d_in[0];
  const float* ffn1_w1  = (const float*)d_in[1];
  const float* ffn1_b1  = (const float*)d_in[2];
  const float* ffn1_w2  = (const float*)d_in[3];
  const float* ffn1_b2  = (const float*)d_in[4];
  const float* ln_att_g = (const float*)d_in[5];
  const float* ln_att_b = (const float*)d_in[6];
  const float* wq       = (const float*)d_in[7];
  const float* bq       = (const float*)d_in[8];
  const float* wk       = (const float*)d_in[9];
  const float* bk       = (const float*)d_in[10];
  const float* wv       = (const float*)d_in[11];
  const float* bv       = (const float*)d_in[12];
  const float* wo_      = (const float*)d_in[13];
  const float* bo       = (const float*)d_in[14];
  const float* cln_g    = (const float*)d_in[15];
  const float* cln_b    = (const float*)d_in[16];
  const float* pw1_w    = (const float*)d_in[17];
  const float* pw1_b    = (const float*)d_in[18];
  const float* dw_w     = (const float*)d_in[19];
  const float* dw_b     = (const float*)d_in[20];
  const float* bn_g     = (const float*)d_in[21];
  const float* bn_b     = (const float*)d_in[22];
  const float* pw2_w    = (const float*)d_in[23];
  const float* pw2_b    = (const float*)d_in[24];
  const float* ffn2_w1  = (const float*)d_in[25];
  const float* ffn2_b1  = (const float*)d_in[26];
  const float* ffn2_w2  = (const float*)d_in[27];
  const float* ffn2_b2  = (const float*)d_in[28];
  const float* ln_out_g = (const float*)d_in[29];
  const float* ln_out_b = (const float*)d_in[30];

  char* wsb = (char*)d_ws;
  const size_t MB = 1u << 20;
  // Region A: residual stream f32 (16 MB)
  float* buf_y = (float*)(wsb);
  // Region B (64 MB, phase-overlaid)
  char* Bre = wsb + 16 * MB;
  float* qb   = (float*)(Bre);             // MHSA: q f32 (16 MB)
  float* kb   = (float*)(Bre + 16 * MB);   //        k f32
  float* vb   = (float*)(Bre + 32 * MB);   //        v f32
  short* lnq  = (short*)(Bre + 48 * MB);   //        LN out bf16 (8 MB)
  short* ctx  = (short*)(Bre + 56 * MB);   //        ctx bf16 (8 MB)
  short* h1   = (short*)(Bre);             // FFN: hidden bf16 (16 MB)
  short* xb   = (short*)(Bre + 16 * MB);   // FFN1: x bf16 (8 MB)
  short* pw1o = (short*)(Bre);             // conv: pw1 out bf16 (32 MB)
  short* gluo = (short*)(Bre + 32 * MB);   //       glu out bf16 (16 MB)
  short* bno  = (short*)(Bre + 48 * MB);   //       bn out bf16 (16 MB)
  short* f2in = (short*)(Bre + 32 * MB);   // FFN2 input bf16 (8 MB, after glu dead)
  // Region C (32 MB, phase-overlaid)
  char* Cre = wsb + 80 * MB;
  short* lnc = (short*)(Cre);              // conv LN out bf16 (8 MB)
  float* dwo = (float*)(Cre);              // dwconv out f32 (32 MB, after lnc dead)
  // Region D: weights / stats (~12 MB)
  char* Dre = wsb + 112 * MB;
  short* w_f1w1 = (short*)(Dre);            // [1024,512]
  short* w_f1w2 = (short*)(Dre + 1 * MB);   // [512,1024]
  short* w_qkv  = (short*)(Dre + 2 * MB);   // [1536,512]
  short* w_wo   = (short*)(Dre + 3 * MB + 512 * 1024);  // [512,512]
  short* w_pw1  = (short*)(Dre + 4 * MB);   // [2048,512]
  short* w_pw2  = (short*)(Dre + 6 * MB);   // [512,1024]
  short* w_f2w1 = (short*)(Dre + 7 * MB);   // [1024,512]
  short* w_f2w2 = (short*)(Dre + 8 * MB);   // [512,1024]
  float* bqkv   = (float*)(Dre + 9 * MB);   // [1536]
  float* ps     = (float*)(Dre + 9 * MB + 8192);
  float* pq     = (float*)(Dre + 10 * MB + 8192);
  float* stats  = (float*)(Dre + 11 * MB + 8192);

  const dim3 blk(256);

  // ---- weight prep (bf16 casts / transposes), every launch (graph-safe)
  cast_bf16_kernel<<<2048, blk, 0, stream>>>(x, xb);                    // 4M elems
  tcast_kernel<<<dim3(32, 16), blk, 0, stream>>>(ffn1_w1, w_f1w1, 512, 1024);
  tcast_kernel<<<dim3(16, 32), blk, 0, stream>>>(ffn1_w2, w_f1w2, 1024, 512);
  tcast_kernel<<<dim3(16, 16), blk, 0, stream>>>(wq, w_qkv, 512, 512);
  tcast_kernel<<<dim3(16, 16), blk, 0, stream>>>(wk, w_qkv + 512 * 512, 512, 512);
  tcast_kernel<<<dim3(16, 16), blk, 0, stream>>>(wv, w_qkv + 1024 * 512, 512, 512);
  tcast_kernel<<<dim3(16, 16), blk, 0, stream>>>(wo_, w_wo, 512, 512);
  cast_bf16_kernel<<<512, blk, 0, stream>>>(pw1_w, w_pw1);              // [2048,512] already [N,K]
  cast_bf16_kernel<<<256, blk, 0, stream>>>(pw2_w, w_pw2);              // [512,1024] already [N,K]
  tcast_kernel<<<dim3(32, 16), blk, 0, stream>>>(ffn2_w1, w_f2w1, 512, 1024);
  tcast_kernel<<<dim3(16, 32), blk, 0, stream>>>(ffn2_w2, w_f2w2, 1024, 512);
  concat3_kernel<<<6, blk, 0, stream>>>(bq, bk, bv, bqkv);

  // ---- FFN1: y = x + 0.5*(swish(x@w1+b1)@w2+b2)
  mgemm<128, 1, false><<<dim3(8, 64), blk, 0, stream>>>(xb, w_f1w1, ffn1_b1, nullptr, nullptr, h1, M_ROWS, 1024, 512);
  mgemm<64, 3, false><<<dim3(8, 64), blk, 0, stream>>>(h1, w_f1w2, ffn1_b2, x, buf_y, nullptr, M_ROWS, 512, 1024);

  // ---- MHSA
  ln_kernel<short><<<M_ROWS, blk, 0, stream>>>(buf_y, ln_att_g, ln_att_b, lnq);
  mgemm<128, 4, false><<<dim3(12, 64), blk, 0, stream>>>(lnq, w_qkv, bqkv, nullptr, qb, nullptr, M_ROWS, 1536, 512);
  rope_kernel<<<8192, blk, 0, stream>>>(qb, 0);  // pos = head index (!)
  rope_kernel<<<8192, blk, 0, stream>>>(kb, 1);  // pos = t
  attn_tile_kernel<<<1024, blk, 0, stream>>>(qb, kb, vb, ctx);
  mgemm<64, 2, false><<<dim3(8, 64), blk, 0, stream>>>(ctx, w_wo, bo, buf_y, buf_y, nullptr, M_ROWS, 512, 512);

  // ---- Conv module
  ln_kernel<short><<<M_ROWS, blk, 0, stream>>>(buf_y, cln_g, cln_b, lnc);
  mgemm<128, 5, false><<<dim3(16, 64), blk, 0, stream>>>(lnc, w_pw1, pw1_b, nullptr, nullptr, pw1o, M_ROWS, 2048, 512);
  glu_kernel<<<4096, blk, 0, stream>>>(pw1o, gluo);
  dwconv_kernel<<<4096, blk, 0, stream>>>(gluo, dw_w, dw_b, dwo);
  bn_stats_kernel<<<256, blk, 0, stream>>>(dwo, ps, pq);
  bn_finalize_kernel<<<4, blk, 0, stream>>>(ps, pq, stats);
  bn_apply_kernel<<<8192, blk, 0, stream>>>(dwo, bn_g, bn_b, stats, bno);
  mgemm<64, 2, true><<<dim3(8, 64), blk, 0, stream>>>(bno, w_pw2, pw2_b, buf_y, buf_y, f2in, M_ROWS, 512, 1024);

  // ---- FFN2
  mgemm<128, 1, false><<<dim3(8, 64), blk, 0, stream>>>(f2in, w_f2w1, ffn2_b1, nullptr, nullptr, h1, M_ROWS, 1024, 512);
  mgemm<64, 3, false><<<dim3(8, 64), blk, 0, stream>>>(h1, w_f2w2, ffn2_b2, buf_y, buf_y, nullptr, M_ROWS, 512, 1024);

  // ---- Final LN -> d_out
  ln_kernel<float><<<M_ROWS, blk, 0, stream>>>(buf_y, ln_out_g, ln_out_b, (float*)d_out);
}

// Round 4
// 450.025 us; speedup vs baseline: 11.3174x; 1.4457x over previous
//
#include <hip/hip_runtime.h>
#include <hip/hip_bf16.h>

// ---------------------------------------------------------------------------
// Conformer block: bf16-MFMA GEMMs + bf16-MFMA flash attention.
// B=8, T=1024, D=512, HID=1024, C=1024, K=31, H=8, dh=64.  M = B*T = 8192.
// ---------------------------------------------------------------------------

#define M_ROWS 8192

using bf16x8 = __attribute__((ext_vector_type(8))) short;
using f32x4  = __attribute__((ext_vector_type(4))) float;
using s8v    = __attribute__((ext_vector_type(8))) short;
using s4v    = __attribute__((ext_vector_type(4))) short;

__device__ __forceinline__ float sigmoid_(float v) { return 1.f / (1.f + expf(-v)); }

__device__ __forceinline__ float bf2f(short s) {
  return __uint_as_float(((unsigned)(unsigned short)s) << 16);
}
__device__ __forceinline__ short f2bf(float f) {
  unsigned u = __float_as_uint(f);
  unsigned r = (u + 0x7fffu + ((u >> 16) & 1u)) >> 16;
  return (short)r;
}

__device__ __forceinline__ void gl16(const void* g, void* l) {
  __builtin_amdgcn_global_load_lds((const __attribute__((address_space(1))) void*)g,
                                   (__attribute__((address_space(3))) void*)l, 16, 0, 0);
}

// ---------------------------------------------------------------------------
// bf16 MFMA GEMM: C[M,N] = epi(A[M,K] @ Bt[N,K]^T + bias). BM=128, BK=32.
// EPI: 0 bias->f32 | 1 swish->bf16 | 2 res+acc+bias->f32 (+DUAL bf16)
//      3 res+0.5*(acc+bias)->f32 | 4 bias, scatter q/k->f32, v->bf16 (B,H,T,64)
//      5 bias->bf16
// ---------------------------------------------------------------------------
template <int BN, int EPI, bool DUAL>
__global__ __launch_bounds__(256) void mgemm(
    const short* __restrict__ A, const short* __restrict__ Bt,
    const float* __restrict__ bias, const float* __restrict__ res,
    float* __restrict__ out, short* __restrict__ outb, int M, int N, int K) {
  constexpr int NF = BN / 32;
  __shared__ __align__(16) short As[128 * 32];
  __shared__ __align__(16) short Bs[BN * 32];
  const int tid = threadIdx.x;
  const int lane = tid & 63, wid = tid >> 6;
  const int wr = wid >> 1, wc = wid & 1;
  const int bm = blockIdx.y << 7, bn = blockIdx.x * BN;
  f32x4 acc[4][NF];
#pragma unroll
  for (int m = 0; m < 4; ++m)
#pragma unroll
    for (int n = 0; n < NF; ++n) acc[m][n] = (f32x4){0.f, 0.f, 0.f, 0.f};
  const short* Ablk = A + (size_t)bm * K;
  const short* Bblk = Bt + (size_t)bn * K;
  const int r0 = tid >> 2, ks = (tid & 3) << 3;  // staging row / k-offset
  for (int k0 = 0; k0 < K; k0 += 32) {
    gl16(Ablk + (size_t)r0 * K + k0 + ks, (char*)As + wid * 1024);
    gl16(Ablk + (size_t)(r0 + 64) * K + k0 + ks, (char*)As + 4096 + wid * 1024);
    gl16(Bblk + (size_t)r0 * K + k0 + ks, (char*)Bs + wid * 1024);
    if (BN == 128)
      gl16(Bblk + (size_t)(r0 + 64) * K + k0 + ks, (char*)Bs + 4096 + wid * 1024);
    __syncthreads();
    bf16x8 af[4], bfr[NF];
    const int arow = wr * 64 + (lane & 15);
    const int brow = wc * (BN / 2) + (lane & 15);
    const int koff = (lane >> 4) << 3;
#pragma unroll
    for (int m = 0; m < 4; ++m)
      af[m] = *reinterpret_cast<const bf16x8*>(&As[(arow + m * 16) * 32 + koff]);
#pragma unroll
    for (int n = 0; n < NF; ++n)
      bfr[n] = *reinterpret_cast<const bf16x8*>(&Bs[(brow + n * 16) * 32 + koff]);
#pragma unroll
    for (int m = 0; m < 4; ++m)
#pragma unroll
      for (int n = 0; n < NF; ++n)
        acc[m][n] = __builtin_amdgcn_mfma_f32_16x16x32_bf16(af[m], bfr[n], acc[m][n], 0, 0, 0);
    __syncthreads();
  }
  const int orow0 = bm + wr * 64 + ((lane >> 4) << 2);
  const int ocol0 = bn + wc * (BN / 2) + (lane & 15);
#pragma unroll
  for (int m = 0; m < 4; ++m) {
#pragma unroll
    for (int n = 0; n < NF; ++n) {
      const int col = ocol0 + n * 16;
      const float bv = bias[col];
#pragma unroll
      for (int r = 0; r < 4; ++r) {
        const int row = orow0 + m * 16 + r;
        float v = acc[m][n][r] + bv;
        if constexpr (EPI == 0) {
          out[(size_t)row * N + col] = v;
        } else if constexpr (EPI == 1) {
          v = v * sigmoid_(v);
          outb[(size_t)row * N + col] = f2bf(v);
        } else if constexpr (EPI == 2) {
          v += res[(size_t)row * N + col];
          out[(size_t)row * N + col] = v;
          if constexpr (DUAL) outb[(size_t)row * N + col] = f2bf(v);
        } else if constexpr (EPI == 3) {
          v = res[(size_t)row * N + col] + 0.5f * v;
          out[(size_t)row * N + col] = v;
        } else if constexpr (EPI == 4) {
          const int sel = col >> 9, cc = col & 511, h = cc >> 6, d = cc & 63;
          const int b_ = row >> 10, t_ = row & 1023;
          const size_t idx = (((size_t)((b_ << 3) + h) << 10) + t_) * 64 + d;
          if (sel < 2) out[(size_t)sel * 4194304 + idx] = v;
          else outb[idx] = f2bf(v);
        } else if constexpr (EPI == 5) {
          outb[(size_t)row * N + col] = f2bf(v);
        }
      }
    }
  }
}

// ---------------------------------------------------------------------------
// LayerNorm over last dim (512). One block (256 threads) per row. OT: float/short(bf16)
// ---------------------------------------------------------------------------
template <typename OT>
__global__ __launch_bounds__(256) void ln_kernel(
    const float* __restrict__ in, const float* __restrict__ g,
    const float* __restrict__ b, OT* __restrict__ out) {
  __shared__ float sm[4];
  const size_t row = blockIdx.x;
  const int tid = threadIdx.x;
  const float* x = in + (row << 9);
  float v0 = x[tid], v1 = x[tid + 256];
  float s = v0 + v1;
  for (int o = 32; o; o >>= 1) s += __shfl_xor(s, o);
  if ((tid & 63) == 0) sm[tid >> 6] = s;
  __syncthreads();
  const float mean = (sm[0] + sm[1] + sm[2] + sm[3]) * (1.f / 512.f);
  __syncthreads();
  const float d0 = v0 - mean, d1 = v1 - mean;
  float q = d0 * d0 + d1 * d1;
  for (int o = 32; o; o >>= 1) q += __shfl_xor(q, o);
  if ((tid & 63) == 0) sm[tid >> 6] = q;
  __syncthreads();
  const float var = (sm[0] + sm[1] + sm[2] + sm[3]) * (1.f / 512.f);
  const float inv = rsqrtf(var + 1e-5f);
  const float o0 = d0 * inv * g[tid] + b[tid];
  const float o1 = d1 * inv * g[tid + 256] + b[tid + 256];
  if constexpr (sizeof(OT) == 2) {
    out[(row << 9) + tid] = f2bf(o0);
    out[(row << 9) + tid + 256] = f2bf(o1);
  } else {
    out[(row << 9) + tid] = o0;
    out[(row << 9) + tid + 256] = o1;
  }
}

// ---------------------------------------------------------------------------
// RoPE in-place on (B,H,T,64) f32. pos_from_t=1: pos=t (k). 0: pos=h (q!).
// ---------------------------------------------------------------------------
__global__ __launch_bounds__(256) void rope_kernel(float* __restrict__ x, int pos_from_t) {
  const size_t i = (size_t)blockIdx.x * 256 + threadIdx.x;  // over B*H*T*32
  const int p = (int)(i & 31);
  const size_t bht = i >> 5;
  const int pos = pos_from_t ? (int)(bht & 1023) : (int)((bht >> 10) & 7);
  const float ang = (float)pos * powf(10000.f, -(float)p * (1.f / 32.f));
  float sn, cs;
  sincosf(ang, &sn, &cs);
  float* base = x + (bht << 6) + (p << 1);
  const float x1 = base[0], x2 = base[1];
  base[0] = x1 * cs - x2 * sn;
  base[1] = x2 * cs + x1 * sn;
}

// ---------------------------------------------------------------------------
// MFMA flash attention. One block (4 waves) per (b,h,64-q-tile). q,k f32
// (B,H,T,64); v bf16 (B,H,T,64); ctx bf16 (B,T,512). Scale folded into Q.
// Wave w owns q rows [w*16, w*16+16). Frag conventions identical to mgemm.
// ---------------------------------------------------------------------------
__global__ __launch_bounds__(256) void attn_mfma_kernel(
    const float* __restrict__ q, const float* __restrict__ k,
    const short* __restrict__ v, short* __restrict__ ctx) {
  __shared__ __align__(16) short Qs[64][72];   // [q][d]   (72*2=144B, 16B-mult)
  __shared__ __align__(16) short Ks[64][72];   // [k][d]
  __shared__ __align__(16) short VsT[64][72];  // [d][k]
  __shared__ __align__(16) short Ps[64][72];   // [q][k]
  const int bx = blockIdx.x;
  const int bh = bx >> 4, qt = bx & 15;
  const int b_ = bh >> 3, h_ = bh & 7;
  const int tid = threadIdx.x, lane = tid & 63, w = tid >> 6;
  const int t0 = qt << 6;
  const float scale = 0.04419417382415922f;  // 1/sqrt(512)
  const float* qbase = q + ((size_t)bh << 16) + ((size_t)t0 << 6);
  const float* kbase = k + ((size_t)bh << 16);
  const short* vbase = v + ((size_t)bh << 16);
  // ---- stage Q (f32 -> bf16, * scale)
#pragma unroll
  for (int it = 0; it < 4; ++it) {
    const int f = tid + (it << 8);
    const int r = f >> 4, dc = (f & 15) << 2;
    const float4 t = *reinterpret_cast<const float4*>(&qbase[(size_t)r * 64 + dc]);
    s4v o = { f2bf(t.x * scale), f2bf(t.y * scale), f2bf(t.z * scale), f2bf(t.w * scale) };
    *reinterpret_cast<s4v*>(&Qs[r][dc]) = o;
  }
  __syncthreads();
  // ---- per-lane Q fragments (wave-row w*16 + (lane&15))
  const int fr = lane & 15, fg = lane >> 4;  // frag row / k-group
  const int koff0 = fg << 3;
  bf16x8 qf[2];
  qf[0] = *reinterpret_cast<const bf16x8*>(&Qs[w * 16 + fr][koff0]);
  qf[1] = *reinterpret_cast<const bf16x8*>(&Qs[w * 16 + fr][32 + koff0]);
  float m[4] = {-1e30f, -1e30f, -1e30f, -1e30f};
  float l[4] = {0.f, 0.f, 0.f, 0.f};
  f32x4 outv[4];
#pragma unroll
  for (int n = 0; n < 4; ++n) outv[n] = (f32x4){0.f, 0.f, 0.f, 0.f};

  for (int k0 = 0; k0 < 1024; k0 += 64) {
    // ---- stage K tile (f32 -> bf16) and V tile (transposed)
#pragma unroll
    for (int it = 0; it < 4; ++it) {
      const int f = tid + (it << 8);
      const int r = f >> 4, dc = (f & 15) << 2;
      const float4 t = *reinterpret_cast<const float4*>(&kbase[(size_t)(k0 + r) * 64 + dc]);
      s4v o = { f2bf(t.x), f2bf(t.y), f2bf(t.z), f2bf(t.w) };
      *reinterpret_cast<s4v*>(&Ks[r][dc]) = o;
    }
    {
      const int r = tid >> 2, cs = (tid & 3) << 4;
      const s8v v0 = *reinterpret_cast<const s8v*>(&vbase[(size_t)(k0 + r) * 64 + cs]);
      const s8v v1 = *reinterpret_cast<const s8v*>(&vbase[(size_t)(k0 + r) * 64 + cs + 8]);
#pragma unroll
      for (int j = 0; j < 8; ++j) VsT[cs + j][r] = v0[j];
#pragma unroll
      for (int j = 0; j < 8; ++j) VsT[cs + 8 + j][r] = v1[j];
    }
    __syncthreads();
    // ---- S = Q @ K^T  (C: row=q-frag-row, col=key)
    f32x4 sacc[4];
#pragma unroll
    for (int n = 0; n < 4; ++n) {
      sacc[n] = (f32x4){0.f, 0.f, 0.f, 0.f};
      const bf16x8 kf0 = *reinterpret_cast<const bf16x8*>(&Ks[n * 16 + fr][koff0]);
      const bf16x8 kf1 = *reinterpret_cast<const bf16x8*>(&Ks[n * 16 + fr][32 + koff0]);
      sacc[n] = __builtin_amdgcn_mfma_f32_16x16x32_bf16(qf[0], kf0, sacc[n], 0, 0, 0);
      sacc[n] = __builtin_amdgcn_mfma_f32_16x16x32_bf16(qf[1], kf1, sacc[n], 0, 0, 0);
    }
    // ---- online softmax (lane holds q-rows fg*4+r, key col n*16+fr)
#pragma unroll
    for (int r = 0; r < 4; ++r) {
      float vm = fmaxf(fmaxf(sacc[0][r], sacc[1][r]), fmaxf(sacc[2][r], sacc[3][r]));
      vm = fmaxf(vm, __shfl_xor(vm, 1));
      vm = fmaxf(vm, __shfl_xor(vm, 2));
      vm = fmaxf(vm, __shfl_xor(vm, 4));
      vm = fmaxf(vm, __shfl_xor(vm, 8));
      const float nm = fmaxf(m[r], vm);
      const float al = __expf(m[r] - nm);
      m[r] = nm;
      float p0 = __expf(sacc[0][r] - nm), p1 = __expf(sacc[1][r] - nm);
      float p2 = __expf(sacc[2][r] - nm), p3 = __expf(sacc[3][r] - nm);
      l[r] = l[r] * al + (p0 + p1 + p2 + p3);  // per-lane partial; reduced at end
      outv[0][r] *= al; outv[1][r] *= al; outv[2][r] *= al; outv[3][r] *= al;
      const int qr = w * 16 + (fg << 2) + r;
      Ps[qr][fr] = f2bf(p0);
      Ps[qr][16 + fr] = f2bf(p1);
      Ps[qr][32 + fr] = f2bf(p2);
      Ps[qr][48 + fr] = f2bf(p3);
    }
    __syncthreads();
    // ---- out += P @ V   (A rows = q from Ps, B cols = d from VsT)
    const bf16x8 pa0 = *reinterpret_cast<const bf16x8*>(&Ps[w * 16 + fr][koff0]);
    const bf16x8 pa1 = *reinterpret_cast<const bf16x8*>(&Ps[w * 16 + fr][32 + koff0]);
#pragma unroll
    for (int n = 0; n < 4; ++n) {
      const bf16x8 vf0 = *reinterpret_cast<const bf16x8*>(&VsT[n * 16 + fr][koff0]);
      const bf16x8 vf1 = *reinterpret_cast<const bf16x8*>(&VsT[n * 16 + fr][32 + koff0]);
      outv[n] = __builtin_amdgcn_mfma_f32_16x16x32_bf16(pa0, vf0, outv[n], 0, 0, 0);
      outv[n] = __builtin_amdgcn_mfma_f32_16x16x32_bf16(pa1, vf1, outv[n], 0, 0, 0);
    }
    __syncthreads();
  }
  // ---- finalize: reduce l across the 16 lanes of the row group, store ctx
#pragma unroll
  for (int r = 0; r < 4; ++r) {
    float L = l[r];
    L += __shfl_xor(L, 1);
    L += __shfl_xor(L, 2);
    L += __shfl_xor(L, 4);
    L += __shfl_xor(L, 8);
    const float inv = 1.f / L;
    const int t = t0 + w * 16 + (fg << 2) + r;
    const size_t base = (((size_t)((b_ << 10) | t)) << 9) + (h_ << 6);
#pragma unroll
    for (int n = 0; n < 4; ++n)
      ctx[base + n * 16 + fr] = f2bf(outv[n][r] * inv);
  }
}

// ---------------------------------------------------------------------------
// f32 -> bf16 cast (8 elems/thread).
// ---------------------------------------------------------------------------
__global__ __launch_bounds__(256) void cast_bf16_kernel(const float* __restrict__ in,
                                                        short* __restrict__ out) {
  const size_t i = (size_t)blockIdx.x * 256 + threadIdx.x;
  const float4 a = *reinterpret_cast<const float4*>(&in[i * 8]);
  const float4 b = *reinterpret_cast<const float4*>(&in[i * 8 + 4]);
  s8v o = { f2bf(a.x), f2bf(a.y), f2bf(a.z), f2bf(a.w),
            f2bf(b.x), f2bf(b.y), f2bf(b.z), f2bf(b.w) };
  *reinterpret_cast<s8v*>(&out[i * 8]) = o;
}

// ---------------------------------------------------------------------------
// Transpose-cast: in [K,N] f32 -> out [N,K] bf16. Grid (N/32, K/32).
// ---------------------------------------------------------------------------
__global__ __launch_bounds__(256) void tcast_kernel(const float* __restrict__ in,
                                                    short* __restrict__ out, int K, int N) {
  __shared__ float t[32][33];
  const int n0 = blockIdx.x << 5, k0 = blockIdx.y << 5;
  const int tx = threadIdx.x & 31, ty = threadIdx.x >> 5;
  for (int r = ty; r < 32; r += 8) t[r][tx] = in[(size_t)(k0 + r) * N + n0 + tx];
  __syncthreads();
  for (int r = ty; r < 32; r += 8) out[(size_t)(n0 + r) * K + k0 + tx] = f2bf(t[tx][r]);
}

__global__ __launch_bounds__(256) void concat3_kernel(const float* a, const float* b,
                                                      const float* c, float* o) {
  const int i = blockIdx.x * 256 + threadIdx.x;  // 1536
  o[i] = i < 512 ? a[i] : (i < 1024 ? b[i - 512] : c[i - 1024]);
}

// ---------------------------------------------------------------------------
// GLU: in bf16 (8192,2048) -> out bf16 (8192,1024). 8 ch/thread.
// ---------------------------------------------------------------------------
__global__ __launch_bounds__(256) void glu_kernel(const short* __restrict__ in,
                                                  short* __restrict__ out) {
  const size_t i = (size_t)blockIdx.x * 256 + threadIdx.x;  // 1M
  const size_t row = i >> 7;
  const int c8 = (int)(i & 127) << 3;
  const s8v av = *reinterpret_cast<const s8v*>(&in[(row << 11) + c8]);
  const s8v gv = *reinterpret_cast<const s8v*>(&in[(row << 11) + 1024 + c8]);
  s8v o;
#pragma unroll
  for (int j = 0; j < 8; ++j) {
    const float a = bf2f(av[j]), g = bf2f(gv[j]);
    o[j] = f2bf(a * sigmoid_(g));
  }
  *reinterpret_cast<s8v*>(&out[i << 3]) = o;
}

// ---------------------------------------------------------------------------
// Depthwise conv K=31 SAME. in bf16 (8,1024,1024), out f32. 8 ch/thread.
// ---------------------------------------------------------------------------
__global__ __launch_bounds__(256) void dwconv_kernel(
    const short* __restrict__ in, const float* __restrict__ w,
    const float* __restrict__ bias, float* __restrict__ out) {
  const size_t i = (size_t)blockIdx.x * 256 + threadIdx.x;  // 1M
  const int c8 = (int)(i & 127) << 3;
  const size_t bt = i >> 7;
  const int t = (int)(bt & 1023);
  const size_t b = bt >> 10;
  float acc[8];
#pragma unroll
  for (int j = 0; j < 8; ++j) acc[j] = bias[c8 + j];
#pragma unroll
  for (int kk = 0; kk < 31; ++kk) {
    const int tt = t + kk - 15;
    if (tt >= 0 && tt < 1024) {
      const s8v xv = *reinterpret_cast<const s8v*>(&in[(b << 20) + ((size_t)tt << 10) + c8]);
      const float4 w0 = *reinterpret_cast<const float4*>(&w[kk * 1024 + c8]);
      const float4 w1 = *reinterpret_cast<const float4*>(&w[kk * 1024 + c8 + 4]);
      acc[0] = fmaf(bf2f(xv[0]), w0.x, acc[0]);
      acc[1] = fmaf(bf2f(xv[1]), w0.y, acc[1]);
      acc[2] = fmaf(bf2f(xv[2]), w0.z, acc[2]);
      acc[3] = fmaf(bf2f(xv[3]), w0.w, acc[3]);
      acc[4] = fmaf(bf2f(xv[4]), w1.x, acc[4]);
      acc[5] = fmaf(bf2f(xv[5]), w1.y, acc[5]);
      acc[6] = fmaf(bf2f(xv[6]), w1.z, acc[6]);
      acc[7] = fmaf(bf2f(xv[7]), w1.w, acc[7]);
    }
  }
  float4 o0 = {acc[0], acc[1], acc[2], acc[3]};
  float4 o1 = {acc[4], acc[5], acc[6], acc[7]};
  *reinterpret_cast<float4*>(&out[(i << 3)]) = o0;
  *reinterpret_cast<float4*>(&out[(i << 3) + 4]) = o1;
}

// ---------------------------------------------------------------------------
// BatchNorm over (B,T): two-stage deterministic reduction; apply+swish -> bf16.
// ---------------------------------------------------------------------------
__global__ __launch_bounds__(256) void bn_stats_kernel(
    const float* __restrict__ y, float* __restrict__ ps, float* __restrict__ pq) {
  const int tid = threadIdx.x;
  const size_t r0 = (size_t)blockIdx.x * 32;
  float s[4] = {0, 0, 0, 0}, q[4] = {0, 0, 0, 0};
  for (int r = 0; r < 32; ++r) {
    const float* row = y + ((r0 + r) << 10);
#pragma unroll
    for (int j = 0; j < 4; ++j) {
      const float v = row[tid + (j << 8)];
      s[j] += v;
      q[j] = fmaf(v, v, q[j]);
    }
  }
#pragma unroll
  for (int j = 0; j < 4; ++j) {
    ps[(size_t)blockIdx.x * 1024 + tid + (j << 8)] = s[j];
    pq[(size_t)blockIdx.x * 1024 + tid + (j << 8)] = q[j];
  }
}

__global__ __launch_bounds__(256) void bn_finalize_kernel(
    const float* __restrict__ ps, const float* __restrict__ pq, float* __restrict__ stats) {
  const int c = blockIdx.x * 256 + threadIdx.x;  // 0..1023
  float s = 0.f, q = 0.f;
  for (int i = 0; i < 256; ++i) {
    s += ps[i * 1024 + c];
    q += pq[i * 1024 + c];
  }
  const float mean = s * (1.f / 8192.f);
  const float var = q * (1.f / 8192.f) - mean * mean;
  stats[c] = mean;
  stats[1024 + c] = rsqrtf(fmaxf(var, 0.f) + 1e-5f);
}

__global__ __launch_bounds__(256) void bn_apply_kernel(
    const float* __restrict__ y, const float* __restrict__ g, const float* __restrict__ b,
    const float* __restrict__ stats, short* __restrict__ out) {
  const size_t i = (size_t)blockIdx.x * 256 + threadIdx.x;  // 2M, 4 elems each
  const size_t f = i << 2;
  const int c = (int)(f & 1023);
  const float4 yv = *reinterpret_cast<const float4*>(&y[f]);
  s4v o;
  float vv[4] = {yv.x, yv.y, yv.z, yv.w};
#pragma unroll
  for (int j = 0; j < 4; ++j) {
    const float v = (vv[j] - stats[c + j]) * stats[1024 + c + j] * g[c + j] + b[c + j];
    o[j] = f2bf(v * sigmoid_(v));
  }
  *reinterpret_cast<s4v*>(&out[f]) = o;
}

// ---------------------------------------------------------------------------
extern "C" void kernel_launch(void* const* d_in, const int* in_sizes, int n_in,
                              void* d_out, int out_size, void* d_ws, size_t ws_size,
                              hipStream_t stream) {
  const float* x        = (const float*)d_in[0];
  const float* ffn1_w1  = (const float*)d_in[1];
  const float* ffn1_b1  = (const float*)d_in[2];
  const float* ffn1_w2  = (const float*)d_in[3];
  const float* ffn1_b2  = (const float*)d_in[4];
  const float* ln_att_g = (const float*)d_in[5];
  const float* ln_att_b = (const float*)d_in[6];
  const float* wq       = (const float*)d_in[7];
  const float* bq       = (const float*)d_in[8];
  const float* wk       = (const float*)d_in[9];
  const float* bk       = (const float*)d_in[10];
  const float* wv       = (const float*)d_in[11];
  const float* bv       = (const float*)d_in[12];
  const float* wo_      = (const float*)d_in[13];
  const float* bo       = (const float*)d_in[14];
  const float* cln_g    = (const float*)d_in[15];
  const float* cln_b    = (const float*)d_in[16];
  const float* pw1_w    = (const float*)d_in[17];
  const float* pw1_b    = (const float*)d_in[18];
  const float* dw_w     = (const float*)d_in[19];
  const float* dw_b     = (const float*)d_in[20];
  const float* bn_g     = (const float*)d_in[21];
  const float* bn_b     = (const float*)d_in[22];
  const float* pw2_w    = (const float*)d_in[23];
  const float* pw2_b    = (const float*)d_in[24];
  const float* ffn2_w1  = (const float*)d_in[25];
  const float* ffn2_b1  = (const float*)d_in[26];
  const float* ffn2_w2  = (const float*)d_in[27];
  const float* ffn2_b2  = (const float*)d_in[28];
  const float* ln_out_g = (const float*)d_in[29];
  const float* ln_out_b = (const float*)d_in[30];

  char* wsb = (char*)d_ws;
  const size_t MB = 1u << 20;
  // Region A: residual stream f32 (16 MB)
  float* buf_y = (float*)(wsb);
  // Region B (64 MB, phase-overlaid)
  char* Bre = wsb + 16 * MB;
  float* qb   = (float*)(Bre);             // MHSA: q f32 (16 MB); k f32 follows
  float* kb   = (float*)(Bre + 16 * MB);
  short* vb16 = (short*)(Bre + 32 * MB);   //        v bf16 (8 MB)
  short* lnq  = (short*)(Bre + 48 * MB);   //        LN out bf16 (8 MB)
  short* ctx  = (short*)(Bre + 56 * MB);   //        ctx bf16 (8 MB)
  short* h1   = (short*)(Bre);             // FFN: hidden bf16 (16 MB)
  short* xb   = (short*)(Bre + 16 * MB);   // FFN1: x bf16 (8 MB)
  short* pw1o = (short*)(Bre);             // conv: pw1 out bf16 (32 MB)
  short* gluo = (short*)(Bre + 32 * MB);   //       glu out bf16 (16 MB)
  short* bno  = (short*)(Bre + 48 * MB);   //       bn out bf16 (16 MB)
  short* f2in = (short*)(Bre + 32 * MB);   // FFN2 input bf16 (8 MB, after glu dead)
  // Region C (32 MB, phase-overlaid)
  char* Cre = wsb + 80 * MB;
  short* lnc = (short*)(Cre);              // conv LN out bf16 (8 MB)
  float* dwo = (float*)(Cre);              // dwconv out f32 (32 MB, after lnc dead)
  // Region D: weights / stats (~12 MB)
  char* Dre = wsb + 112 * MB;
  short* w_f1w1 = (short*)(Dre);            // [1024,512]
  short* w_f1w2 = (short*)(Dre + 1 * MB);   // [512,1024]
  short* w_qkv  = (short*)(Dre + 2 * MB);   // [1536,512]
  short* w_wo   = (short*)(Dre + 3 * MB + 512 * 1024);  // [512,512]
  short* w_pw1  = (short*)(Dre + 4 * MB);   // [2048,512]
  short* w_pw2  = (short*)(Dre + 6 * MB);   // [512,1024]
  short* w_f2w1 = (short*)(Dre + 7 * MB);   // [1024,512]
  short* w_f2w2 = (short*)(Dre + 8 * MB);   // [512,1024]
  float* bqkv   = (float*)(Dre + 9 * MB);   // [1536]
  float* ps     = (float*)(Dre + 9 * MB + 8192);
  float* pq     = (float*)(Dre + 10 * MB + 8192);
  float* stats  = (float*)(Dre + 11 * MB + 8192);

  const dim3 blk(256);

  // ---- weight prep (bf16 casts / transposes), every launch (graph-safe)
  cast_bf16_kernel<<<2048, blk, 0, stream>>>(x, xb);                    // 4M elems
  tcast_kernel<<<dim3(32, 16), blk, 0, stream>>>(ffn1_w1, w_f1w1, 512, 1024);
  tcast_kernel<<<dim3(16, 32), blk, 0, stream>>>(ffn1_w2, w_f1w2, 1024, 512);
  tcast_kernel<<<dim3(16, 16), blk, 0, stream>>>(wq, w_qkv, 512, 512);
  tcast_kernel<<<dim3(16, 16), blk, 0, stream>>>(wk, w_qkv + 512 * 512, 512, 512);
  tcast_kernel<<<dim3(16, 16), blk, 0, stream>>>(wv, w_qkv + 1024 * 512, 512, 512);
  tcast_kernel<<<dim3(16, 16), blk, 0, stream>>>(wo_, w_wo, 512, 512);
  cast_bf16_kernel<<<512, blk, 0, stream>>>(pw1_w, w_pw1);              // [2048,512] already [N,K]
  cast_bf16_kernel<<<256, blk, 0, stream>>>(pw2_w, w_pw2);              // [512,1024] already [N,K]
  tcast_kernel<<<dim3(32, 16), blk, 0, stream>>>(ffn2_w1, w_f2w1, 512, 1024);
  tcast_kernel<<<dim3(16, 32), blk, 0, stream>>>(ffn2_w2, w_f2w2, 1024, 512);
  concat3_kernel<<<6, blk, 0, stream>>>(bq, bk, bv, bqkv);

  // ---- FFN1: y = x + 0.5*(swish(x@w1+b1)@w2+b2)
  mgemm<128, 1, false><<<dim3(8, 64), blk, 0, stream>>>(xb, w_f1w1, ffn1_b1, nullptr, nullptr, h1, M_ROWS, 1024, 512);
  mgemm<64, 3, false><<<dim3(8, 64), blk, 0, stream>>>(h1, w_f1w2, ffn1_b2, x, buf_y, nullptr, M_ROWS, 512, 1024);

  // ---- MHSA
  ln_kernel<short><<<M_ROWS, blk, 0, stream>>>(buf_y, ln_att_g, ln_att_b, lnq);
  mgemm<128, 4, false><<<dim3(12, 64), blk, 0, stream>>>(lnq, w_qkv, bqkv, nullptr, qb, vb16, M_ROWS, 1536, 512);
  rope_kernel<<<8192, blk, 0, stream>>>(qb, 0);  // pos = head index (!)
  rope_kernel<<<8192, blk, 0, stream>>>(kb, 1);  // pos = t
  attn_mfma_kernel<<<1024, blk, 0, stream>>>(qb, kb, vb16, ctx);
  mgemm<64, 2, false><<<dim3(8, 64), blk, 0, stream>>>(ctx, w_wo, bo, buf_y, buf_y, nullptr, M_ROWS, 512, 512);

  // ---- Conv module
  ln_kernel<short><<<M_ROWS, blk, 0, stream>>>(buf_y, cln_g, cln_b, lnc);
  mgemm<128, 5, false><<<dim3(16, 64), blk, 0, stream>>>(lnc, w_pw1, pw1_b, nullptr, nullptr, pw1o, M_ROWS, 2048, 512);
  glu_kernel<<<4096, blk, 0, stream>>>(pw1o, gluo);
  dwconv_kernel<<<4096, blk, 0, stream>>>(gluo, dw_w, dw_b, dwo);
  bn_stats_kernel<<<256, blk, 0, stream>>>(dwo, ps, pq);
  bn_finalize_kernel<<<4, blk, 0, stream>>>(ps, pq, stats);
  bn_apply_kernel<<<8192, blk, 0, stream>>>(dwo, bn_g, bn_b, stats, bno);
  mgemm<64, 2, true><<<dim3(8, 64), blk, 0, stream>>>(bno, w_pw2, pw2_b, buf_y, buf_y, f2in, M_ROWS, 512, 1024);

  // ---- FFN2
  mgemm<128, 1, false><<<dim3(8, 64), blk, 0, stream>>>(f2in, w_f2w1, ffn2_b1, nullptr, nullptr, h1, M_ROWS, 1024, 512);
  mgemm<64, 3, false><<<dim3(8, 64), blk, 0, stream>>>(h1, w_f2w2, ffn2_b2, buf_y, buf_y, nullptr, M_ROWS, 512, 1024);

  // ---- Final LN -> d_out
  ln_kernel<float><<<M_ROWS, blk, 0, stream>>>(buf_y, ln_out_g, ln_out_b, (float*)d_out);
}

// Round 6
// 426.986 us; speedup vs baseline: 11.9281x; 1.0540x over previous
//
#include <hip/hip_runtime.h>
#include <hip/hip_bf16.h>

// ---------------------------------------------------------------------------
// Conformer block: bf16-MFMA GEMMs + bf16-MFMA flash attention.
// RoPE fused into QKV epilogue; GLU fused into pw1 epilogue (packed weights);
// BN chain in bf16.  B=8, T=1024, D=512, HID=1024, C=1024, K=31, H=8, dh=64.
// ---------------------------------------------------------------------------

#define M_ROWS 8192

using bf16x8 = __attribute__((ext_vector_type(8))) short;
using f32x4  = __attribute__((ext_vector_type(4))) float;
using s8v    = __attribute__((ext_vector_type(8))) short;
using s4v    = __attribute__((ext_vector_type(4))) short;

__device__ __forceinline__ float sigmoid_(float v) { return 1.f / (1.f + expf(-v)); }

__device__ __forceinline__ float bf2f(short s) {
  return __uint_as_float(((unsigned)(unsigned short)s) << 16);
}
__device__ __forceinline__ short f2bf(float f) {
  unsigned u = __float_as_uint(f);
  unsigned r = (u + 0x7fffu + ((u >> 16) & 1u)) >> 16;
  return (short)r;
}

__device__ __forceinline__ void gl16(const void* g, void* l) {
  __builtin_amdgcn_global_load_lds((const __attribute__((address_space(1))) void*)g,
                                   (__attribute__((address_space(3))) void*)l, 16, 0, 0);
}

// ---------------------------------------------------------------------------
// bf16 MFMA GEMM: C[M,N] = epi(A[M,K] @ Bt[N,K]^T + bias). BM=128, BK=32.
// EPI: 0 bias->f32 | 1 swish->bf16 | 2 res+acc+bias->f32 (+DUAL bf16)
//      3 res+0.5*(acc+bias)->f32 | 5 bias->bf16
//      4 QKV: rope(q,pos=h,*scale)/rope(k,pos=t)->bf16 (B,H,T,64); v->bf16 (B,H,64,T)
//      6 pw1+GLU (packed interleaved weights): a*sigmoid(gate)->bf16 (8192,1024)
// ---------------------------------------------------------------------------
template <int BN, int EPI, bool DUAL>
__global__ __launch_bounds__(256) void mgemm(
    const short* __restrict__ A, const short* __restrict__ Bt,
    const float* __restrict__ bias, const float* __restrict__ res,
    float* __restrict__ out, short* __restrict__ outb, int M, int N, int K) {
  constexpr int NF = BN / 32;
  __shared__ __align__(16) short As[128 * 32];
  __shared__ __align__(16) short Bs[BN * 32];
  const int tid = threadIdx.x;
  const int lane = tid & 63, wid = tid >> 6;
  const int wr = wid >> 1, wc = wid & 1;
  const int bm = blockIdx.y << 7, bn = blockIdx.x * BN;
  f32x4 acc[4][NF];
#pragma unroll
  for (int m = 0; m < 4; ++m)
#pragma unroll
    for (int n = 0; n < NF; ++n) acc[m][n] = (f32x4){0.f, 0.f, 0.f, 0.f};
  const short* Ablk = A + (size_t)bm * K;
  const short* Bblk = Bt + (size_t)bn * K;
  const int r0 = tid >> 2, ks = (tid & 3) << 3;  // staging row / k-offset
  for (int k0 = 0; k0 < K; k0 += 32) {
    gl16(Ablk + (size_t)r0 * K + k0 + ks, (char*)As + wid * 1024);
    gl16(Ablk + (size_t)(r0 + 64) * K + k0 + ks, (char*)As + 4096 + wid * 1024);
    gl16(Bblk + (size_t)r0 * K + k0 + ks, (char*)Bs + wid * 1024);
    if (BN == 128)
      gl16(Bblk + (size_t)(r0 + 64) * K + k0 + ks, (char*)Bs + 4096 + wid * 1024);
    __syncthreads();
    bf16x8 af[4], bfr[NF];
    const int arow = wr * 64 + (lane & 15);
    const int brow = wc * (BN / 2) + (lane & 15);
    const int koff = (lane >> 4) << 3;
#pragma unroll
    for (int m = 0; m < 4; ++m)
      af[m] = *reinterpret_cast<const bf16x8*>(&As[(arow + m * 16) * 32 + koff]);
#pragma unroll
    for (int n = 0; n < NF; ++n)
      bfr[n] = *reinterpret_cast<const bf16x8*>(&Bs[(brow + n * 16) * 32 + koff]);
#pragma unroll
    for (int m = 0; m < 4; ++m)
#pragma unroll
      for (int n = 0; n < NF; ++n)
        acc[m][n] = __builtin_amdgcn_mfma_f32_16x16x32_bf16(af[m], bfr[n], acc[m][n], 0, 0, 0);
    __syncthreads();
  }
  const int orow0 = bm + wr * 64 + ((lane >> 4) << 2);
  const int ocol0 = bn + wc * (BN / 2) + (lane & 15);

  if constexpr (EPI == 4) {
    // ---- QKV epilogue with fused RoPE. sel: 0=q (pos=h, *scale), 1=k (pos=t), 2=v^T.
    const int sel = bn >> 9;
    if (sel == 2) {
#pragma unroll
      for (int m = 0; m < 4; ++m) {
        const int row0 = orow0 + m * 16;
        const int b_ = row0 >> 10, t_ = row0 & 1023;
#pragma unroll
        for (int n = 0; n < NF; ++n) {
          const int col = ocol0 + n * 16;
          const int h = (col >> 6) & 7, d = col & 63;
          const float bv = bias[col];
          s4v pk;
#pragma unroll
          for (int r = 0; r < 4; ++r) pk[r] = f2bf(acc[m][n][r] + bv);
          *reinterpret_cast<s4v*>(
              &outb[(size_t)8388608 + (((size_t)((b_ << 3) + h)) << 16) + ((size_t)d << 10) + t_]) = pk;
        }
      }
    } else {
      const float qsc = (sel == 0) ? 0.04419417382415922f : 1.f;  // 1/sqrt(512)
#pragma unroll
      for (int n = 0; n < NF; ++n) {
        const int col = ocol0 + n * 16;
        const int h = (col >> 6) & 7, d = col & 63;
        const float invf = exp2f(-(float)(d >> 1) * 0.41524101186092f);  // 10000^(-p/32)
        const float bv = bias[col];
        float cs0 = 0.f, sn0 = 0.f;
        if (sel == 0) sincosf((float)h * invf, &sn0, &cs0);
#pragma unroll
        for (int m = 0; m < 4; ++m) {
#pragma unroll
          for (int r = 0; r < 4; ++r) {
            const int row = orow0 + m * 16 + r;
            const int b_ = row >> 10, t_ = row & 1023;
            float cs = cs0, sn = sn0;
            if (sel == 1) sincosf((float)t_ * invf, &sn, &cs);
            float vv = acc[m][n][r] + bv;
            const float pv = __shfl_xor(vv, 1);
            float o = ((lane & 1) == 0) ? (vv * cs - pv * sn) : (vv * cs + pv * sn);
            o *= qsc;
            outb[(size_t)sel * 4194304 + (((size_t)((b_ << 3) + h)) << 16) + ((size_t)t_ << 6) + d] =
                f2bf(o);
          }
        }
      }
    }
  } else if constexpr (EPI == 6) {
    // ---- pw1 + GLU: packed weights put (a, gate) in frags (2np, 2np+1) of same lane.
    const int j = bn >> 7;
#pragma unroll
    for (int m = 0; m < 4; ++m) {
#pragma unroll
      for (int np = 0; np < NF / 2; ++np) {
        const int gc = (j << 6) + ((wc * 2 + np) << 4) + (lane & 15);  // GLU out col
        const float ba = bias[gc];
        const float bg = bias[1024 + gc];
#pragma unroll
        for (int r = 0; r < 4; ++r) {
          const int row = orow0 + m * 16 + r;
          const float a = acc[m][2 * np][r] + ba;
          const float g = acc[m][2 * np + 1][r] + bg;
          outb[(size_t)row * 1024 + gc] = f2bf(a * sigmoid_(g));
        }
      }
    }
  } else {
#pragma unroll
    for (int m = 0; m < 4; ++m) {
#pragma unroll
      for (int n = 0; n < NF; ++n) {
        const int col = ocol0 + n * 16;
        const float bv = bias[col];
#pragma unroll
        for (int r = 0; r < 4; ++r) {
          const int row = orow0 + m * 16 + r;
          float v = acc[m][n][r] + bv;
          if constexpr (EPI == 0) {
            out[(size_t)row * N + col] = v;
          } else if constexpr (EPI == 1) {
            v = v * sigmoid_(v);
            outb[(size_t)row * N + col] = f2bf(v);
          } else if constexpr (EPI == 2) {
            v += res[(size_t)row * N + col];
            out[(size_t)row * N + col] = v;
            if constexpr (DUAL) outb[(size_t)row * N + col] = f2bf(v);
          } else if constexpr (EPI == 3) {
            v = res[(size_t)row * N + col] + 0.5f * v;
            out[(size_t)row * N + col] = v;
          } else if constexpr (EPI == 5) {
            outb[(size_t)row * N + col] = f2bf(v);
          }
        }
      }
    }
  }
}

// ---------------------------------------------------------------------------
// LayerNorm over last dim (512). One block (256 threads) per row.
// ---------------------------------------------------------------------------
template <typename OT>
__global__ __launch_bounds__(256) void ln_kernel(
    const float* __restrict__ in, const float* __restrict__ g,
    const float* __restrict__ b, OT* __restrict__ out) {
  __shared__ float sm[4];
  const size_t row = blockIdx.x;
  const int tid = threadIdx.x;
  const float* x = in + (row << 9);
  float v0 = x[tid], v1 = x[tid + 256];
  float s = v0 + v1;
  for (int o = 32; o; o >>= 1) s += __shfl_xor(s, o);
  if ((tid & 63) == 0) sm[tid >> 6] = s;
  __syncthreads();
  const float mean = (sm[0] + sm[1] + sm[2] + sm[3]) * (1.f / 512.f);
  __syncthreads();
  const float d0 = v0 - mean, d1 = v1 - mean;
  float q = d0 * d0 + d1 * d1;
  for (int o = 32; o; o >>= 1) q += __shfl_xor(q, o);
  if ((tid & 63) == 0) sm[tid >> 6] = q;
  __syncthreads();
  const float var = (sm[0] + sm[1] + sm[2] + sm[3]) * (1.f / 512.f);
  const float inv = rsqrtf(var + 1e-5f);
  const float o0 = d0 * inv * g[tid] + b[tid];
  const float o1 = d1 * inv * g[tid + 256] + b[tid + 256];
  if constexpr (sizeof(OT) == 2) {
    out[(row << 9) + tid] = f2bf(o0);
    out[(row << 9) + tid + 256] = f2bf(o1);
  } else {
    out[(row << 9) + tid] = o0;
    out[(row << 9) + tid + 256] = o1;
  }
}

// ---------------------------------------------------------------------------
// MFMA flash attention. One block (4 waves) per (b,h,64-q-tile).
// q,k bf16 (B,H,T,64) pre-roped (q pre-scaled); v bf16 TRANSPOSED (B,H,64,T).
// ctx bf16 (B,T,512). Wave w owns q rows [w*16, w*16+16).
// ---------------------------------------------------------------------------
__global__ __launch_bounds__(256) void attn_mfma_kernel(
    const short* __restrict__ q, const short* __restrict__ k,
    const short* __restrict__ vt, short* __restrict__ ctx) {
  __shared__ __align__(16) short Qs[64][72];   // [q][d]
  __shared__ __align__(16) short Ks[64][72];   // [k][d]
  __shared__ __align__(16) short VsT[64][72];  // [d][k]
  __shared__ __align__(16) short Ps[64][72];   // [q][k]
  const int bx = blockIdx.x;
  const int bh = bx >> 4, qt = bx & 15;
  const int b_ = bh >> 3, h_ = bh & 7;
  const int tid = threadIdx.x, lane = tid & 63, w = tid >> 6;
  const int t0 = qt << 6;
  const short* qbase = q + ((size_t)bh << 16) + ((size_t)t0 << 6);
  const short* kbase = k + ((size_t)bh << 16);
  const short* vtbase = vt + ((size_t)bh << 16);
  const int sr = tid >> 2, scg = (tid & 3) << 4;  // staging: row 0..63, colgroup 0/16/32/48
  // ---- stage Q (copy)
  {
    const s8v a = *reinterpret_cast<const s8v*>(&qbase[(size_t)sr * 64 + scg]);
    const s8v b = *reinterpret_cast<const s8v*>(&qbase[(size_t)sr * 64 + scg + 8]);
    *reinterpret_cast<s8v*>(&Qs[sr][scg]) = a;
    *reinterpret_cast<s8v*>(&Qs[sr][scg + 8]) = b;
  }
  __syncthreads();
  const int fr = lane & 15, fg = lane >> 4;
  const int koff0 = fg << 3;
  bf16x8 qf[2];
  qf[0] = *reinterpret_cast<const bf16x8*>(&Qs[w * 16 + fr][koff0]);
  qf[1] = *reinterpret_cast<const bf16x8*>(&Qs[w * 16 + fr][32 + koff0]);
  float m[4] = {-1e30f, -1e30f, -1e30f, -1e30f};
  float l[4] = {0.f, 0.f, 0.f, 0.f};
  f32x4 outv[4];
#pragma unroll
  for (int n = 0; n < 4; ++n) outv[n] = (f32x4){0.f, 0.f, 0.f, 0.f};

  for (int k0 = 0; k0 < 1024; k0 += 64) {
    // ---- stage K tile and V^T tile (pure copies)
    {
      const s8v a = *reinterpret_cast<const s8v*>(&kbase[(size_t)(k0 + sr) * 64 + scg]);
      const s8v b = *reinterpret_cast<const s8v*>(&kbase[(size_t)(k0 + sr) * 64 + scg + 8]);
      *reinterpret_cast<s8v*>(&Ks[sr][scg]) = a;
      *reinterpret_cast<s8v*>(&Ks[sr][scg + 8]) = b;
      const s8v c = *reinterpret_cast<const s8v*>(&vtbase[((size_t)sr << 10) + k0 + scg]);
      const s8v d = *reinterpret_cast<const s8v*>(&vtbase[((size_t)sr << 10) + k0 + scg + 8]);
      *reinterpret_cast<s8v*>(&VsT[sr][scg]) = c;
      *reinterpret_cast<s8v*>(&VsT[sr][scg + 8]) = d;
    }
    __syncthreads();
    // ---- S = Q @ K^T
    f32x4 sacc[4];
#pragma unroll
    for (int n = 0; n < 4; ++n) {
      sacc[n] = (f32x4){0.f, 0.f, 0.f, 0.f};
      const bf16x8 kf0 = *reinterpret_cast<const bf16x8*>(&Ks[n * 16 + fr][koff0]);
      const bf16x8 kf1 = *reinterpret_cast<const bf16x8*>(&Ks[n * 16 + fr][32 + koff0]);
      sacc[n] = __builtin_amdgcn_mfma_f32_16x16x32_bf16(qf[0], kf0, sacc[n], 0, 0, 0);
      sacc[n] = __builtin_amdgcn_mfma_f32_16x16x32_bf16(qf[1], kf1, sacc[n], 0, 0, 0);
    }
    // ---- online softmax
#pragma unroll
    for (int r = 0; r < 4; ++r) {
      float vm = fmaxf(fmaxf(sacc[0][r], sacc[1][r]), fmaxf(sacc[2][r], sacc[3][r]));
      vm = fmaxf(vm, __shfl_xor(vm, 1));
      vm = fmaxf(vm, __shfl_xor(vm, 2));
      vm = fmaxf(vm, __shfl_xor(vm, 4));
      vm = fmaxf(vm, __shfl_xor(vm, 8));
      const float nm = fmaxf(m[r], vm);
      const float al = __expf(m[r] - nm);
      m[r] = nm;
      float p0 = __expf(sacc[0][r] - nm), p1 = __expf(sacc[1][r] - nm);
      float p2 = __expf(sacc[2][r] - nm), p3 = __expf(sacc[3][r] - nm);
      l[r] = l[r] * al + (p0 + p1 + p2 + p3);
      outv[0][r] *= al; outv[1][r] *= al; outv[2][r] *= al; outv[3][r] *= al;
      const int qr = w * 16 + (fg << 2) + r;
      Ps[qr][fr] = f2bf(p0);
      Ps[qr][16 + fr] = f2bf(p1);
      Ps[qr][32 + fr] = f2bf(p2);
      Ps[qr][48 + fr] = f2bf(p3);
    }
    __syncthreads();
    // ---- out += P @ V
    const bf16x8 pa0 = *reinterpret_cast<const bf16x8*>(&Ps[w * 16 + fr][koff0]);
    const bf16x8 pa1 = *reinterpret_cast<const bf16x8*>(&Ps[w * 16 + fr][32 + koff0]);
#pragma unroll
    for (int n = 0; n < 4; ++n) {
      const bf16x8 vf0 = *reinterpret_cast<const bf16x8*>(&VsT[n * 16 + fr][koff0]);
      const bf16x8 vf1 = *reinterpret_cast<const bf16x8*>(&VsT[n * 16 + fr][32 + koff0]);
      outv[n] = __builtin_amdgcn_mfma_f32_16x16x32_bf16(pa0, vf0, outv[n], 0, 0, 0);
      outv[n] = __builtin_amdgcn_mfma_f32_16x16x32_bf16(pa1, vf1, outv[n], 0, 0, 0);
    }
    __syncthreads();
  }
#pragma unroll
  for (int r = 0; r < 4; ++r) {
    float L = l[r];
    L += __shfl_xor(L, 1);
    L += __shfl_xor(L, 2);
    L += __shfl_xor(L, 4);
    L += __shfl_xor(L, 8);
    const float inv = 1.f / L;
    const int t = t0 + w * 16 + (fg << 2) + r;
    const size_t base = (((size_t)((b_ << 10) | t)) << 9) + (h_ << 6);
#pragma unroll
    for (int n = 0; n < 4; ++n)
      ctx[base + n * 16 + fr] = f2bf(outv[n][r] * inv);
  }
}

// ---------------------------------------------------------------------------
// f32 -> bf16 cast (8 elems/thread).
// ---------------------------------------------------------------------------
__global__ __launch_bounds__(256) void cast_bf16_kernel(const float* __restrict__ in,
                                                        short* __restrict__ out) {
  const size_t i = (size_t)blockIdx.x * 256 + threadIdx.x;
  const float4 a = *reinterpret_cast<const float4*>(&in[i * 8]);
  const float4 b = *reinterpret_cast<const float4*>(&in[i * 8 + 4]);
  s8v o = { f2bf(a.x), f2bf(a.y), f2bf(a.z), f2bf(a.w),
            f2bf(b.x), f2bf(b.y), f2bf(b.z), f2bf(b.w) };
  *reinterpret_cast<s8v*>(&out[i * 8]) = o;
}

// ---------------------------------------------------------------------------
// pw1 weight pack: [2048][512] f32 -> interleaved [2048][512] bf16 so that a
// block's 128-col tile holds (a,gate) pairs in adjacent 16-col frags.
// packed row pc: j=pc>>7, s=(pc>>4)&7, fr=pc&15; orig = (s&1)*1024 + j*64 + (s>>1)*16 + fr.
// ---------------------------------------------------------------------------
__global__ __launch_bounds__(256) void pack_pw1_kernel(const float* __restrict__ w,
                                                       short* __restrict__ out) {
  const int idx = blockIdx.x * 256 + threadIdx.x;  // 2048*64
  const int pc = idx >> 6, kk = (idx & 63) << 3;
  const int j = pc >> 7, s = (pc >> 4) & 7, fr = pc & 15;
  const int oc = ((s & 1) << 10) + (j << 6) + ((s >> 1) << 4) + fr;
  const float4 a = *reinterpret_cast<const float4*>(&w[(size_t)oc * 512 + kk]);
  const float4 b = *reinterpret_cast<const float4*>(&w[(size_t)oc * 512 + kk + 4]);
  s8v o = { f2bf(a.x), f2bf(a.y), f2bf(a.z), f2bf(a.w),
            f2bf(b.x), f2bf(b.y), f2bf(b.z), f2bf(b.w) };
  *reinterpret_cast<s8v*>(&out[(size_t)pc * 512 + kk]) = o;
}

// ---------------------------------------------------------------------------
// Transpose-cast: in [K,N] f32 -> out [N,K] bf16. Grid (N/32, K/32).
// ---------------------------------------------------------------------------
__global__ __launch_bounds__(256) void tcast_kernel(const float* __restrict__ in,
                                                    short* __restrict__ out, int K, int N) {
  __shared__ float t[32][33];
  const int n0 = blockIdx.x << 5, k0 = blockIdx.y << 5;
  const int tx = threadIdx.x & 31, ty = threadIdx.x >> 5;
  for (int r = ty; r < 32; r += 8) t[r][tx] = in[(size_t)(k0 + r) * N + n0 + tx];
  __syncthreads();
  for (int r = ty; r < 32; r += 8) out[(size_t)(n0 + r) * K + k0 + tx] = f2bf(t[tx][r]);
}

__global__ __launch_bounds__(256) void concat3_kernel(const float* a, const float* b,
                                                      const float* c, float* o) {
  const int i = blockIdx.x * 256 + threadIdx.x;  // 1536
  o[i] = i < 512 ? a[i] : (i < 1024 ? b[i - 512] : c[i - 1024]);
}

// ---------------------------------------------------------------------------
// Depthwise conv K=31 SAME. in bf16 (8,1024,1024), out bf16. 8 ch/thread.
// ---------------------------------------------------------------------------
__global__ __launch_bounds__(256) void dwconv_kernel(
    const short* __restrict__ in, const float* __restrict__ w,
    const float* __restrict__ bias, short* __restrict__ out) {
  const size_t i = (size_t)blockIdx.x * 256 + threadIdx.x;  // 1M
  const int c8 = (int)(i & 127) << 3;
  const size_t bt = i >> 7;
  const int t = (int)(bt & 1023);
  const size_t b = bt >> 10;
  float acc[8];
#pragma unroll
  for (int j = 0; j < 8; ++j) acc[j] = bias[c8 + j];
#pragma unroll
  for (int kk = 0; kk < 31; ++kk) {
    const int tt = t + kk - 15;
    if (tt >= 0 && tt < 1024) {
      const s8v xv = *reinterpret_cast<const s8v*>(&in[(b << 20) + ((size_t)tt << 10) + c8]);
      const float4 w0 = *reinterpret_cast<const float4*>(&w[kk * 1024 + c8]);
      const float4 w1 = *reinterpret_cast<const float4*>(&w[kk * 1024 + c8 + 4]);
      acc[0] = fmaf(bf2f(xv[0]), w0.x, acc[0]);
      acc[1] = fmaf(bf2f(xv[1]), w0.y, acc[1]);
      acc[2] = fmaf(bf2f(xv[2]), w0.z, acc[2]);
      acc[3] = fmaf(bf2f(xv[3]), w0.w, acc[3]);
      acc[4] = fmaf(bf2f(xv[4]), w1.x, acc[4]);
      acc[5] = fmaf(bf2f(xv[5]), w1.y, acc[5]);
      acc[6] = fmaf(bf2f(xv[6]), w1.z, acc[6]);
      acc[7] = fmaf(bf2f(xv[7]), w1.w, acc[7]);
    }
  }
  s8v o;
#pragma unroll
  for (int j = 0; j < 8; ++j) o[j] = f2bf(acc[j]);
  *reinterpret_cast<s8v*>(&out[i << 3]) = o;
}

// ---------------------------------------------------------------------------
// BatchNorm over (B,T) on bf16 y: two-stage deterministic reduction; apply+swish.
// ---------------------------------------------------------------------------
__global__ __launch_bounds__(256) void bn_stats_kernel(
    const short* __restrict__ y, float* __restrict__ ps, float* __restrict__ pq) {
  const int tid = threadIdx.x;
  const int c4 = tid << 2;
  const size_t r0 = (size_t)blockIdx.x * 32;
  float s[4] = {0, 0, 0, 0}, q[4] = {0, 0, 0, 0};
  for (int r = 0; r < 32; ++r) {
    const s4v v = *reinterpret_cast<const s4v*>(&y[((r0 + r) << 10) + c4]);
#pragma unroll
    for (int j = 0; j < 4; ++j) {
      const float f = bf2f(v[j]);
      s[j] += f;
      q[j] = fmaf(f, f, q[j]);
    }
  }
#pragma unroll
  for (int j = 0; j < 4; ++j) {
    ps[(size_t)blockIdx.x * 1024 + c4 + j] = s[j];
    pq[(size_t)blockIdx.x * 1024 + c4 + j] = q[j];
  }
}

__global__ __launch_bounds__(256) void bn_finalize_kernel(
    const float* __restrict__ ps, const float* __restrict__ pq, float* __restrict__ stats) {
  const int c = blockIdx.x * 256 + threadIdx.x;  // 0..1023
  float s = 0.f, q = 0.f;
  for (int i = 0; i < 256; ++i) {
    s += ps[i * 1024 + c];
    q += pq[i * 1024 + c];
  }
  const float mean = s * (1.f / 8192.f);
  const float var = q * (1.f / 8192.f) - mean * mean;
  stats[c] = mean;
  stats[1024 + c] = rsqrtf(fmaxf(var, 0.f) + 1e-5f);
}

__global__ __launch_bounds__(256) void bn_apply_kernel(
    const short* __restrict__ y, const float* __restrict__ g, const float* __restrict__ b,
    const float* __restrict__ stats, short* __restrict__ out) {
  const size_t i = (size_t)blockIdx.x * 256 + threadIdx.x;  // 2M, 4 elems each
  const size_t f = i << 2;
  const int c = (int)(f & 1023);
  const s4v yv = *reinterpret_cast<const s4v*>(&y[f]);
  s4v o;
#pragma unroll
  for (int j = 0; j < 4; ++j) {
    const float v = (bf2f(yv[j]) - stats[c + j]) * stats[1024 + c + j] * g[c + j] + b[c + j];
    o[j] = f2bf(v * sigmoid_(v));
  }
  *reinterpret_cast<s4v*>(&out[f]) = o;
}

// ---------------------------------------------------------------------------
extern "C" void kernel_launch(void* const* d_in, const int* in_sizes, int n_in,
                              void* d_out, int out_size, void* d_ws, size_t ws_size,
                              hipStream_t stream) {
  const float* x        = (const float*)d_in[0];
  const float* ffn1_w1  = (const float*)d_in[1];
  const float* ffn1_b1  = (const float*)d_in[2];
  const float* ffn1_w2  = (const float*)d_in[3];
  const float* ffn1_b2  = (const float*)d_in[4];
  const float* ln_att_g = (const float*)d_in[5];
  const float* ln_att_b = (const float*)d_in[6];
  const float* wq       = (const float*)d_in[7];
  const float* bq       = (const float*)d_in[8];
  const float* wk       = (const float*)d_in[9];
  const float* bk       = (const float*)d_in[10];
  const float* wv       = (const float*)d_in[11];
  const float* bv       = (const float*)d_in[12];
  const float* wo_      = (const float*)d_in[13];
  const float* bo       = (const float*)d_in[14];
  const float* cln_g    = (const float*)d_in[15];
  const float* cln_b    = (const float*)d_in[16];
  const float* pw1_w    = (const float*)d_in[17];
  const float* pw1_b    = (const float*)d_in[18];
  const float* dw_w     = (const float*)d_in[19];
  const float* dw_b     = (const float*)d_in[20];
  const float* bn_g     = (const float*)d_in[21];
  const float* bn_b     = (const float*)d_in[22];
  const float* pw2_w    = (const float*)d_in[23];
  const float* pw2_b    = (const float*)d_in[24];
  const float* ffn2_w1  = (const float*)d_in[25];
  const float* ffn2_b1  = (const float*)d_in[26];
  const float* ffn2_w2  = (const float*)d_in[27];
  const float* ffn2_b2  = (const float*)d_in[28];
  const float* ln_out_g = (const float*)d_in[29];
  const float* ln_out_b = (const float*)d_in[30];

  char* wsb = (char*)d_ws;
  const size_t MB = 1u << 20;
  // Region A: residual stream f32 (16 MB)
  float* buf_y = (float*)(wsb);
  // Region B (64 MB, phase-overlaid)
  char* Bre = wsb + 16 * MB;
  short* qkv16 = (short*)(Bre);            // MHSA: q,k (B,H,T,64) + v^T (B,H,64,T), 24 MB
  short* lnq  = (short*)(Bre + 48 * MB);   //        LN out bf16 (8 MB)
  short* ctx  = (short*)(Bre + 56 * MB);   //        ctx bf16 (8 MB)
  short* h1   = (short*)(Bre);             // FFN: hidden bf16 (16 MB)
  short* xb   = (short*)(Bre + 16 * MB);   // FFN1: x bf16 (8 MB)
  short* gluo = (short*)(Bre);             // conv: fused pw1+GLU out bf16 (16 MB)
  short* bno  = (short*)(Bre + 48 * MB);   //       bn out bf16 (16 MB)
  short* f2in = (short*)(Bre + 32 * MB);   // FFN2 input bf16 (8 MB)
  // Region C (32 MB, phase-overlaid)
  char* Cre = wsb + 80 * MB;
  short* lnc  = (short*)(Cre);             // conv LN out bf16 (8 MB)
  short* dwo16= (short*)(Cre + 8 * MB);    // dwconv out bf16 (16 MB)
  // Region D: weights / stats (~12 MB)
  char* Dre = wsb + 112 * MB;
  short* w_f1w1 = (short*)(Dre);            // [1024,512]
  short* w_f1w2 = (short*)(Dre + 1 * MB);   // [512,1024]
  short* w_qkv  = (short*)(Dre + 2 * MB);   // [1536,512]
  short* w_wo   = (short*)(Dre + 3 * MB + 512 * 1024);  // [512,512]
  short* w_pw1  = (short*)(Dre + 4 * MB);   // [2048,512] packed-interleaved
  short* w_pw2  = (short*)(Dre + 6 * MB);   // [512,1024]
  short* w_f2w1 = (short*)(Dre + 7 * MB);   // [1024,512]
  short* w_f2w2 = (short*)(Dre + 8 * MB);   // [512,1024]
  float* bqkv   = (float*)(Dre + 9 * MB);   // [1536]
  float* ps     = (float*)(Dre + 9 * MB + 8192);
  float* pq     = (float*)(Dre + 10 * MB + 8192);
  float* stats  = (float*)(Dre + 11 * MB + 8192);

  const dim3 blk(256);

  // ---- input/weight prep (bf16 casts / transposes / packs), graph-safe
  cast_bf16_kernel<<<2048, blk, 0, stream>>>(x, xb);
  tcast_kernel<<<dim3(32, 16), blk, 0, stream>>>(ffn1_w1, w_f1w1, 512, 1024);
  tcast_kernel<<<dim3(16, 32), blk, 0, stream>>>(ffn1_w2, w_f1w2, 1024, 512);
  tcast_kernel<<<dim3(16, 16), blk, 0, stream>>>(wq, w_qkv, 512, 512);
  tcast_kernel<<<dim3(16, 16), blk, 0, stream>>>(wk, w_qkv + 512 * 512, 512, 512);
  tcast_kernel<<<dim3(16, 16), blk, 0, stream>>>(wv, w_qkv + 1024 * 512, 512, 512);
  tcast_kernel<<<dim3(16, 16), blk, 0, stream>>>(wo_, w_wo, 512, 512);
  pack_pw1_kernel<<<512, blk, 0, stream>>>(pw1_w, w_pw1);
  cast_bf16_kernel<<<256, blk, 0, stream>>>(pw2_w, w_pw2);
  tcast_kernel<<<dim3(32, 16), blk, 0, stream>>>(ffn2_w1, w_f2w1, 512, 1024);
  tcast_kernel<<<dim3(16, 32), blk, 0, stream>>>(ffn2_w2, w_f2w2, 1024, 512);
  concat3_kernel<<<6, blk, 0, stream>>>(bq, bk, bv, bqkv);

  // ---- FFN1: y = x + 0.5*(swish(x@w1+b1)@w2+b2)
  mgemm<128, 1, false><<<dim3(8, 64), blk, 0, stream>>>(xb, w_f1w1, ffn1_b1, nullptr, nullptr, h1, M_ROWS, 1024, 512);
  mgemm<64, 3, false><<<dim3(8, 64), blk, 0, stream>>>(h1, w_f1w2, ffn1_b2, x, buf_y, nullptr, M_ROWS, 512, 1024);

  // ---- MHSA (RoPE fused into QKV epilogue; q pre-scaled; v stored transposed)
  ln_kernel<short><<<M_ROWS, blk, 0, stream>>>(buf_y, ln_att_g, ln_att_b, lnq);
  mgemm<128, 4, false><<<dim3(12, 64), blk, 0, stream>>>(lnq, w_qkv, bqkv, nullptr, nullptr, qkv16, M_ROWS, 1536, 512);
  attn_mfma_kernel<<<1024, blk, 0, stream>>>(qkv16, qkv16 + 4194304, qkv16 + 8388608, ctx);
  mgemm<64, 2, false><<<dim3(8, 64), blk, 0, stream>>>(ctx, w_wo, bo, buf_y, buf_y, nullptr, M_ROWS, 512, 512);

  // ---- Conv module (pw1+GLU fused; BN chain in bf16)
  ln_kernel<short><<<M_ROWS, blk, 0, stream>>>(buf_y, cln_g, cln_b, lnc);
  mgemm<128, 6, false><<<dim3(16, 64), blk, 0, stream>>>(lnc, w_pw1, pw1_b, nullptr, nullptr, gluo, M_ROWS, 2048, 512);
  dwconv_kernel<<<4096, blk, 0, stream>>>(gluo, dw_w, dw_b, dwo16);
  bn_stats_kernel<<<256, blk, 0, stream>>>(dwo16, ps, pq);
  bn_finalize_kernel<<<4, blk, 0, stream>>>(ps, pq, stats);
  bn_apply_kernel<<<8192, blk, 0, stream>>>(dwo16, bn_g, bn_b, stats, bno);
  mgemm<64, 2, true><<<dim3(8, 64), blk, 0, stream>>>(bno, w_pw2, pw2_b, buf_y, buf_y, f2in, M_ROWS, 512, 1024);

  // ---- FFN2
  mgemm<128, 1, false><<<dim3(8, 64), blk, 0, stream>>>(f2in, w_f2w1, ffn2_b1, nullptr, nullptr, h1, M_ROWS, 1024, 512);
  mgemm<64, 3, false><<<dim3(8, 64), blk, 0, stream>>>(h1, w_f2w2, ffn2_b2, buf_y, buf_y, nullptr, M_ROWS, 512, 1024);

  // ---- Final LN -> d_out
  ln_kernel<float><<<M_ROWS, blk, 0, stream>>>(buf_y, ln_out_g, ln_out_b, (float*)d_out);
}